// Round 8
// baseline (374.596 us; speedup 1.0000x reference)
//
#include <hip/hip_runtime.h>
#include <cstdint>
#include <cmath>

#define DEVINL __device__ __forceinline__

using f32x4  = __attribute__((ext_vector_type(4))) float;
using bf16x8 = __attribute__((ext_vector_type(8))) __bf16;
using u16x8  = __attribute__((ext_vector_type(8))) unsigned short;
using u16x4  = __attribute__((ext_vector_type(4))) unsigned short;
using fl4    = __attribute__((ext_vector_type(4))) float;

DEVINL float bf2f(unsigned short h) {
    unsigned int u = ((unsigned int)h) << 16;
    float f; __builtin_memcpy(&f, &u, 4); return f;
}
DEVINL unsigned short f2bf(float f) {
    unsigned int u; __builtin_memcpy(&u, &f, 4);
    u += 0x7FFFu + ((u >> 16) & 1u);   // RNE
    return (unsigned short)(u >> 16);
}

DEVINL void gload_lds16(const unsigned short* g, unsigned short* l) {
    __builtin_amdgcn_global_load_lds(
        (__attribute__((address_space(1))) void*)g,
        (__attribute__((address_space(3))) void*)l,
        16, 0, 0);
}

// ---------------------------------------------------------------------------
// f32 -> bf16 elementwise
__global__ __launch_bounds__(256)
void f2b_kernel(const float* __restrict__ x, unsigned short* __restrict__ y, int n)
{
    const int i = (blockIdx.x * 256 + threadIdx.x) * 4;
    if (i < n) {
        fl4 v = *(const fl4*)(x + i);
        u16x4 o;
#pragma unroll
        for (int j = 0; j < 4; ++j) o[j] = f2bf(v[j]);
        *(u16x4*)(y + i) = o;
    }
}

// f32 -> split hi/lo bf16
__global__ __launch_bounds__(256)
void f2b_split(const float* __restrict__ x, unsigned short* __restrict__ yh,
               unsigned short* __restrict__ yl, int n)
{
    const int i = (blockIdx.x * 256 + threadIdx.x) * 4;
    if (i < n) {
        fl4 v = *(const fl4*)(x + i);
        u16x4 oh, ol;
#pragma unroll
        for (int j = 0; j < 4; ++j) {
            oh[j] = f2bf(v[j]);
            ol[j] = f2bf(v[j] - bf2f(oh[j]));
        }
        *(u16x4*)(yh + i) = oh;
        *(u16x4*)(yl + i) = ol;
    }
}

// transpose + split: yh/yl[c*R + r] = split(x[r*C + c])
__global__ __launch_bounds__(256)
void tr_f2b_split(const float* __restrict__ x, unsigned short* __restrict__ yh,
                  unsigned short* __restrict__ yl, int R, int Ccols)
{
    const int o = blockIdx.x * 256 + threadIdx.x;
    if (o < R * Ccols) {
        const int e = o / R, d = o - e * R;
        const float v = x[d * Ccols + e];
        const unsigned short h = f2bf(v);
        yh[o] = h;
        yl[o] = f2bf(v - bf2f(h));
    }
}

// ---------------------------------------------------------------------------
// Split-bf16 3-pass GEMM: C = alpha * (Ah+Al)[M,K] @ (Bh+Bl)[N,K]^T
// OUTMODE 0: f32 out (out1). OUTMODE 1: split bf16 out (out1=hi, out2=lo).
template<int BM, int BN, int WAVES_M, int WAVES_N, int OUTMODE>
__global__ __launch_bounds__(256)
void gemm_bt3(const unsigned short* __restrict__ Ah, const unsigned short* __restrict__ Al,
              const unsigned short* __restrict__ Bh, const unsigned short* __restrict__ Bl,
              void* __restrict__ out1, unsigned short* __restrict__ out2,
              int N, int K, long sA, long sB, long sC, float alpha)
{
    constexpr int BK = 32;
    constexpr int WM = BM / WAVES_M, WN = BN / WAVES_N;
    constexpr int MT = WM / 16, NT = WN / 16;
    __shared__ alignas(16) unsigned short Ash[BM * BK], Asl[BM * BK];
    __shared__ alignas(16) unsigned short Bsh[BN * BK], Bsl[BN * BK];

    const int bz = blockIdx.z;
    Ah += (long)bz * sA; Al += (long)bz * sA;
    Bh += (long)bz * sB; Bl += (long)bz * sB;
    const int row0 = blockIdx.y * BM, col0 = blockIdx.x * BN;
    const int tid = threadIdx.x, l = tid & 63, w = tid >> 6;
    const int wm = w / WAVES_N, wn = w % WAVES_N;
    const int fr = l & 15, fq = l >> 4;

    f32x4 acc[MT][NT] = {};
    constexpr int ACALLS = (BM * BK) / (256 * 8);
    constexpr int BCALLS = (BN * BK) / (256 * 8);

    for (int kt = 0; kt < K; kt += BK) {
#pragma unroll
        for (int c = 0; c < ACALLS; ++c) {
            const int e = (c * 256 + tid) * 8;
            const long g = (long)(row0 + (e >> 5)) * K + kt + (e & 31);
            gload_lds16(Ah + g, &Ash[e]);
            gload_lds16(Al + g, &Asl[e]);
        }
#pragma unroll
        for (int c = 0; c < BCALLS; ++c) {
            const int e = (c * 256 + tid) * 8;
            const long g = (long)(col0 + (e >> 5)) * K + kt + (e & 31);
            gload_lds16(Bh + g, &Bsh[e]);
            gload_lds16(Bl + g, &Bsl[e]);
        }
        __syncthreads();

        bf16x8 afh[MT], afl[MT], bfh[NT], bfl[NT];
#pragma unroll
        for (int m = 0; m < MT; ++m) {
            const int o = (wm * WM + m * 16 + fr) * BK + fq * 8;
            afh[m] = __builtin_bit_cast(bf16x8, *(const u16x8*)&Ash[o]);
            afl[m] = __builtin_bit_cast(bf16x8, *(const u16x8*)&Asl[o]);
        }
#pragma unroll
        for (int n = 0; n < NT; ++n) {
            const int o = (wn * WN + n * 16 + fr) * BK + fq * 8;
            bfh[n] = __builtin_bit_cast(bf16x8, *(const u16x8*)&Bsh[o]);
            bfl[n] = __builtin_bit_cast(bf16x8, *(const u16x8*)&Bsl[o]);
        }
#pragma unroll
        for (int m = 0; m < MT; ++m)
#pragma unroll
            for (int n = 0; n < NT; ++n) {
                acc[m][n] = __builtin_amdgcn_mfma_f32_16x16x32_bf16(afh[m], bfh[n], acc[m][n], 0, 0, 0);
                acc[m][n] = __builtin_amdgcn_mfma_f32_16x16x32_bf16(afh[m], bfl[n], acc[m][n], 0, 0, 0);
                acc[m][n] = __builtin_amdgcn_mfma_f32_16x16x32_bf16(afl[m], bfh[n], acc[m][n], 0, 0, 0);
            }
        __syncthreads();
    }

#pragma unroll
    for (int m = 0; m < MT; ++m) {
        const int gr = row0 + wm * WM + m * 16 + fq * 4;
#pragma unroll
        for (int n = 0; n < NT; ++n) {
            const int gc = col0 + wn * WN + n * 16 + fr;
#pragma unroll
            for (int j = 0; j < 4; ++j) {
                const float v = acc[m][n][j] * alpha;
                const long idx = (long)bz * sC + (long)(gr + j) * N + gc;
                if (OUTMODE == 0) {
                    ((float*)out1)[idx] = v;
                } else {
                    const unsigned short h = f2bf(v);
                    ((unsigned short*)out1)[idx] = h;
                    out2[idx] = f2bf(v - bf2f(h));
                }
            }
        }
    }
}

// ---------------------------------------------------------------------------
// Plain bf16 GEMM: C[M,N] = alpha * A[M,K] @ B[N,K]^T
template<int BM, int BN, int WAVES_M, int WAVES_N, bool OUT_F32>
__global__ __launch_bounds__(256)
void gemm_bt(const unsigned short* __restrict__ A,
             const unsigned short* __restrict__ B,
             void* __restrict__ Cv,
             int N, int K, long sA, long sB, long sC, float alpha)
{
    constexpr int BK = 32;
    constexpr int WM = BM / WAVES_M, WN = BN / WAVES_N;
    constexpr int MT = WM / 16, NT = WN / 16;
    __shared__ alignas(16) unsigned short As[BM * BK];
    __shared__ alignas(16) unsigned short Bs[BN * BK];

    const int bz = blockIdx.z;
    A += (long)bz * sA;
    B += (long)bz * sB;
    const int row0 = blockIdx.y * BM, col0 = blockIdx.x * BN;
    const int tid = threadIdx.x, l = tid & 63, w = tid >> 6;
    const int wm = w / WAVES_N, wn = w % WAVES_N;
    const int fr = l & 15, fq = l >> 4;

    f32x4 acc[MT][NT] = {};
    constexpr int ACALLS = (BM * BK) / (256 * 8);
    constexpr int BCALLS = (BN * BK) / (256 * 8);

    for (int kt = 0; kt < K; kt += BK) {
#pragma unroll
        for (int c = 0; c < ACALLS; ++c) {
            const int e = (c * 256 + tid) * 8;
            gload_lds16(A + (long)(row0 + (e >> 5)) * K + kt + (e & 31), &As[e]);
        }
#pragma unroll
        for (int c = 0; c < BCALLS; ++c) {
            const int e = (c * 256 + tid) * 8;
            gload_lds16(B + (long)(col0 + (e >> 5)) * K + kt + (e & 31), &Bs[e]);
        }
        __syncthreads();

        bf16x8 af[MT], bfr[NT];
#pragma unroll
        for (int m = 0; m < MT; ++m)
            af[m] = __builtin_bit_cast(bf16x8, *(const u16x8*)&As[(wm * WM + m * 16 + fr) * BK + fq * 8]);
#pragma unroll
        for (int n = 0; n < NT; ++n)
            bfr[n] = __builtin_bit_cast(bf16x8, *(const u16x8*)&Bs[(wn * WN + n * 16 + fr) * BK + fq * 8]);
#pragma unroll
        for (int m = 0; m < MT; ++m)
#pragma unroll
            for (int n = 0; n < NT; ++n)
                acc[m][n] = __builtin_amdgcn_mfma_f32_16x16x32_bf16(af[m], bfr[n], acc[m][n], 0, 0, 0);
        __syncthreads();
    }

#pragma unroll
    for (int m = 0; m < MT; ++m) {
        const int gr = row0 + wm * WM + m * 16 + fq * 4;
#pragma unroll
        for (int n = 0; n < NT; ++n) {
            const int gc = col0 + wn * WN + n * 16 + fr;
#pragma unroll
            for (int j = 0; j < 4; ++j) {
                const float v = acc[m][n][j] * alpha;
                if (OUT_F32) ((float*)Cv)[(long)bz * sC + (long)(gr + j) * N + gc] = v;
                else ((unsigned short*)Cv)[(long)bz * sC + (long)(gr + j) * N + gc] = f2bf(v);
            }
        }
    }
}

// ---------------------------------------------------------------------------
// C[M,N] = rowscale(row) * A[M,K] @ B[K,N]   (bf16; B row-major [K x N]).
template<int BM, int BN, int WAVES_M, int WAVES_N>
__global__ __launch_bounds__(256)
void gemm_nt(const unsigned short* __restrict__ A,
             const unsigned short* __restrict__ Bm,
             unsigned short* __restrict__ C,
             const float* __restrict__ rowscale,
             int N, int K, long sA, long sB, long sC, int rsS)
{
    constexpr int BK = 32;
    constexpr int WM = BM / WAVES_M, WN = BN / WAVES_N;
    constexpr int MT = WM / 16, NT = WN / 16;
    __shared__ alignas(16) unsigned short As[BM * BK];
    __shared__ alignas(16) unsigned short Bs[BN * BK];   // Bs[col*BK + k]

    const int bz = blockIdx.z;
    A += (long)bz * sA;
    Bm += (long)bz * sB;
    const int row0 = blockIdx.y * BM, col0 = blockIdx.x * BN;
    const int tid = threadIdx.x, l = tid & 63, w = tid >> 6;
    const int wm = w / WAVES_N, wn = w % WAVES_N;
    const int fr = l & 15, fq = l >> 4;

    f32x4 acc[MT][NT] = {};
    constexpr int ACALLS = (BM * BK) / (256 * 8);
    constexpr int TPR = BN / 8;
    constexpr int RPP = 256 / TPR;
    const int br = tid / TPR, bc8 = (tid % TPR) * 8;

    for (int kt = 0; kt < K; kt += BK) {
#pragma unroll
        for (int c = 0; c < ACALLS; ++c) {
            const int e = (c * 256 + tid) * 8;
            gload_lds16(A + (long)(row0 + (e >> 5)) * K + kt + (e & 31), &As[e]);
        }
#pragma unroll
        for (int p = 0; p < BK / RPP; ++p) {
            const int r = p * RPP + br;
            u16x8 vv = *(const u16x8*)(Bm + (long)(kt + r) * N + col0 + bc8);
#pragma unroll
            for (int j = 0; j < 8; ++j) Bs[(bc8 + j) * BK + r] = vv[j];
        }
        __syncthreads();

        bf16x8 af[MT], bfr[NT];
#pragma unroll
        for (int m = 0; m < MT; ++m)
            af[m] = __builtin_bit_cast(bf16x8, *(const u16x8*)&As[(wm * WM + m * 16 + fr) * BK + fq * 8]);
#pragma unroll
        for (int n = 0; n < NT; ++n)
            bfr[n] = __builtin_bit_cast(bf16x8, *(const u16x8*)&Bs[(wn * WN + n * 16 + fr) * BK + fq * 8]);
#pragma unroll
        for (int m = 0; m < MT; ++m)
#pragma unroll
            for (int n = 0; n < NT; ++n)
                acc[m][n] = __builtin_amdgcn_mfma_f32_16x16x32_bf16(af[m], bfr[n], acc[m][n], 0, 0, 0);
        __syncthreads();
    }

#pragma unroll
    for (int m = 0; m < MT; ++m) {
        const int gr = row0 + wm * WM + m * 16 + fq * 4;
#pragma unroll
        for (int n = 0; n < NT; ++n) {
            const int gc = col0 + wn * WN + n * 16 + fr;
#pragma unroll
            for (int j = 0; j < 4; ++j) {
                float v = acc[m][n][j];
                if (rowscale) v *= rowscale[(long)bz * rsS + gr + j];
                C[(long)bz * sC + (long)(gr + j) * N + gc] = f2bf(v);
            }
        }
    }
}

// ---------------------------------------------------------------------------
// LayerNorm over D=768, f32 in -> split hi/lo bf16 out.
__global__ __launch_bounds__(256)
void ln_rows_split(const float* __restrict__ x,
                   const float* __restrict__ gamma,
                   const float* __restrict__ beta,
                   unsigned short* __restrict__ yh,
                   unsigned short* __restrict__ yl)
{
    constexpr int D = 768;
    const long row = blockIdx.x;
    const int tid = threadIdx.x;
    const float* xr = x + row * D;
    float v[8]; float s = 0.f, s2 = 0.f;
    const bool act = tid < (D / 8);
    if (act) {
        fl4 a = *(const fl4*)(xr + tid * 8);
        fl4 b = *(const fl4*)(xr + tid * 8 + 4);
#pragma unroll
        for (int j = 0; j < 4; ++j) { v[j] = a[j]; v[4 + j] = b[j]; }
#pragma unroll
        for (int j = 0; j < 8; ++j) { s += v[j]; s2 += v[j] * v[j]; }
    }
#pragma unroll
    for (int o = 32; o; o >>= 1) { s += __shfl_down(s, o); s2 += __shfl_down(s2, o); }
    __shared__ float rs[4], rs2[4];
    if ((tid & 63) == 0) { rs[tid >> 6] = s; rs2[tid >> 6] = s2; }
    __syncthreads();
    const float st  = rs[0] + rs[1] + rs[2] + rs[3];
    const float s2t = rs2[0] + rs2[1] + rs2[2] + rs2[3];
    const float mu  = st / (float)D;
    const float var = s2t / (float)D - mu * mu;
    const float r   = rsqrtf(var + 1e-5f);
    if (act) {
        fl4 g1 = *(const fl4*)(gamma + tid * 8), g2 = *(const fl4*)(gamma + tid * 8 + 4);
        fl4 b1 = *(const fl4*)(beta + tid * 8),  b2 = *(const fl4*)(beta + tid * 8 + 4);
        u16x8 oh, ol;
#pragma unroll
        for (int j = 0; j < 8; ++j) {
            const float g = (j < 4) ? g1[j] : g2[j - 4];
            const float bb = (j < 4) ? b1[j] : b2[j - 4];
            const float y = (v[j] - mu) * r * g + bb;
            oh[j] = f2bf(y);
            ol[j] = f2bf(y - bf2f(oh[j]));
        }
        *(u16x8*)(yh + row * D + tid * 8) = oh;
        *(u16x8*)(yl + row * D + tid * 8) = ol;
    }
}

// ---------------------------------------------------------------------------
// normmax (alpha=5) over C=64 slots per (b,n) column; in-place logits->attn f32.
__global__ __launch_bounds__(256)
void normmax_cols(float* __restrict__ logits, const int* __restrict__ mask)
{
    constexpr int N = 1024, C = 64;
    const int b = blockIdx.y;
    const int tid = threadIdx.x, l = tid & 63, w = tid >> 6;
    const int n = blockIdx.x * 64 + w * 16 + (l & 15);
    const int cb = (l >> 4) * 16;
    float* Lb = logits + (long)b * C * N + n;
    const int m = mask[b * N + n];

    float z[16];
#pragma unroll
    for (int i = 0; i < 16; ++i) z[i] = m ? Lb[(cb + i) * N] : 0.f;

    float mx = z[0];
#pragma unroll
    for (int i = 1; i < 16; ++i) mx = fmaxf(mx, z[i]);
    mx = fmaxf(mx, __shfl_xor(mx, 16));
    mx = fmaxf(mx, __shfl_xor(mx, 32));

    float lo = mx - 1.f, hi = mx;
    for (int it = 0; it < 50; ++it) {
        const float tau = 0.5f * (lo + hi);
        float f = 0.f;
#pragma unroll
        for (int i = 0; i < 16; ++i) {
            const float u = fmaxf(z[i] - tau, 0.f);
            f += u * sqrtf(sqrtf(u));       // u^(5/4)
        }
        f += __shfl_xor(f, 16);
        f += __shfl_xor(f, 32);
        if (f >= 1.f) lo = tau; else hi = tau;
    }
    const float tau = 0.5f * (lo + hi);
    float sv[16]; float ss = 0.f;
#pragma unroll
    for (int i = 0; i < 16; ++i) {
        const float u = fmaxf(z[i] - tau, 0.f);
        sv[i] = sqrtf(sqrtf(u));            // u^(1/4)
        ss += sv[i];
    }
    ss += __shfl_xor(ss, 16);
    ss += __shfl_xor(ss, 32);
    const float inv = 1.f / ss;
#pragma unroll
    for (int i = 0; i < 16; ++i) Lb[(cb + i) * N] = m ? sv[i] * inv : 0.f;
}

// ---------------------------------------------------------------------------
// Per (b,c) row: f32 attn to d_out, bf16 copy for P-gemm, invsum.
__global__ __launch_bounds__(256)
void attn_finish(const float* __restrict__ attn,
                 float* __restrict__ attn_out_f32,
                 unsigned short* __restrict__ attn_b16,
                 float* __restrict__ invsum)
{
    constexpr int N = 1024;
    const long row = blockIdx.x;
    const int tid = threadIdx.x;
    const fl4 v = *(const fl4*)(attn + row * N + tid * 4);
    float s = v[0] + v[1] + v[2] + v[3];
#pragma unroll
    for (int o = 32; o; o >>= 1) s += __shfl_down(s, o);
    __shared__ float rs[4];
    if ((tid & 63) == 0) rs[tid >> 6] = s;
    __syncthreads();
    const float tot = rs[0] + rs[1] + rs[2] + rs[3];
    if (tid == 0) invsum[row] = 1.f / (tot + 1e-8f);
    u16x4 o1;
#pragma unroll
    for (int j = 0; j < 4; ++j) o1[j] = f2bf(v[j]);
    *(fl4*)(attn_out_f32 + row * N + tid * 4) = v;
    *(u16x4*)(attn_b16 + row * N + tid * 4) = o1;
}

// ---------------------------------------------------------------------------
// torch GRUCell gates (r,z,n order), h_new = (1-z)*n + z*h. f32 in/out.
__global__ __launch_bounds__(256)
void gru_gates(const float* __restrict__ gi, const float* __restrict__ gh,
               const float* __restrict__ b_ih, const float* __restrict__ b_hh,
               const float* __restrict__ h, float* __restrict__ out)
{
    constexpr int D = 768;
    const int idx = blockIdx.x * 256 + threadIdx.x;
    const int row = idx / D, d = idx - row * D;
    const float* gir = gi + (long)row * 3 * D;
    const float* ghr = gh + (long)row * 3 * D;
    const float ir  = gir[d]         + b_ih[d];
    const float iz  = gir[D + d]     + b_ih[D + d];
    const float in_ = gir[2 * D + d] + b_ih[2 * D + d];
    const float hr  = ghr[d]         + b_hh[d];
    const float hz  = ghr[D + d]     + b_hh[D + d];
    const float hn  = ghr[2 * D + d] + b_hh[2 * D + d];
    const float r   = 1.f / (1.f + expf(-(ir + hr)));
    const float zg  = 1.f / (1.f + expf(-(iz + hz)));
    const float ng  = tanhf(in_ + r * hn);
    out[idx] = (1.f - zg) * ng + zg * h[idx];
}

extern "C" void kernel_launch(void* const* d_in, const int* in_sizes, int n_in,
                              void* d_out, int out_size, void* d_ws, size_t ws_size,
                              hipStream_t stream)
{
    const float* features = (const float*)d_in[0];
    const float* slots    = (const float*)d_in[1];
    const int*   mask     = (const int*)d_in[2];
    const float* lnf_g = (const float*)d_in[3];
    const float* lnf_b = (const float*)d_in[4];
    const float* lns_g = (const float*)d_in[5];
    const float* lns_b = (const float*)d_in[6];
    const float* Wk  = (const float*)d_in[7];
    const float* Wv  = (const float*)d_in[8];
    const float* Wq  = (const float*)d_in[9];
    const float* Wih = (const float*)d_in[10];
    const float* Whh = (const float*)d_in[11];
    const float* bih = (const float*)d_in[12];
    const float* bhh = (const float*)d_in[13];

    constexpr int B = 32, N = 1024, C = 64, D = 768;
    char* ws = (char*)d_ws;
    // ---- workspace layout, peak 132.7 MB
    // region 1: f_hi [LN .. P gemm], then conv2 weights + gi/gh
    unsigned short* f_hi = (unsigned short*)(ws + 0);          // 50,331,648
    float*          gi   = (float*)(ws + 0);                   // [gi gemm .. gru]
    float*          gh   = (float*)(ws + 18874368);            // [gh gemm .. gru]
    unsigned short* Wihb = (unsigned short*)(ws + 37748736);   // [conv2 .. gi gemm]
    unsigned short* Whhb = (unsigned short*)(ws + 41287680);   // [conv2 .. gh gemm]
    unsigned short* slb  = (unsigned short*)(ws + 44826624);   // [conv2 .. gh gemm]
    unsigned short* Wvb  = (unsigned short*)(ws + 47972352);   // [conv2 .. upd gemm]
    // region 2: f_lo [LN .. logits gemm], then attn byproducts
    unsigned short* f_lo = (unsigned short*)(ws + 50331648);   // 50,331,648
    unsigned short* ab16 = (unsigned short*)(ws + 50331648);   // [attn_finish .. P gemm]
    unsigned short* Pbf  = (unsigned short*)(ws + 54525952);   // [P gemm .. upd gemm]
    unsigned short* updb = (unsigned short*)(ws + 57671680);   // [upd gemm .. gi gemm]
    // region 3: small pool
    float*          lg    = (float*)(ws + 100663296);          //  8,388,608
    float*          inv   = (float*)(ws + 109051904);          //      8,192
    unsigned short* s_hi  = (unsigned short*)(ws + 109060096); //  3,145,728
    unsigned short* s_lo  = (unsigned short*)(ws + 112205824);
    unsigned short* q_hi  = (unsigned short*)(ws + 115351552);
    unsigned short* q_lo  = (unsigned short*)(ws + 118497280);
    unsigned short* qk_hi = (unsigned short*)(ws + 121643008);
    unsigned short* qk_lo = (unsigned short*)(ws + 124788736);
    unsigned short* Wq_hi = (unsigned short*)(ws + 127934464); //  1,179,648
    unsigned short* Wq_lo = (unsigned short*)(ws + 129114112);
    unsigned short* WkT_hi= (unsigned short*)(ws + 130293760);
    unsigned short* WkT_lo= (unsigned short*)(ws + 131473408); // ends 132,653,056

    float* out_slots = (float*)d_out;
    float* out_attn  = out_slots + (long)B * C * D;

    // conv1: logits-path weights (split)
    f2b_split<<<(D * D) / 1024, 256, 0, stream>>>(Wq, Wq_hi, Wq_lo, D * D);
    tr_f2b_split<<<(D * D + 255) / 256, 256, 0, stream>>>(Wk, WkT_hi, WkT_lo, D, D);

    ln_rows_split<<<B * N, 256, 0, stream>>>(features, lnf_g, lnf_b, f_hi, f_lo);
    ln_rows_split<<<B * C, 256, 0, stream>>>(slots, lns_g, lns_b, s_hi, s_lo);

    // q = s @ Wq^T   [2048 x 768], split out
    gemm_bt3<64, 128, 1, 4, 1><<<dim3(D / 128, (B * C) / 64, 1), 256, 0, stream>>>(
        s_hi, s_lo, Wq_hi, Wq_lo, q_hi, q_lo, D, D, 0, 0, 0, 1.f);
    // qk = q @ (WkT)^T   [2048 x 768], split out
    gemm_bt3<64, 128, 1, 4, 1><<<dim3(D / 128, (B * C) / 64, 1), 256, 0, stream>>>(
        q_hi, q_lo, WkT_hi, WkT_lo, qk_hi, qk_lo, D, D, 0, 0, 0, 1.f);
    // logits[b] = qk_b @ f_b^T / sqrt(768)   [64 x 1024] f32
    gemm_bt3<64, 128, 1, 4, 0><<<dim3(N / 128, 1, B), 256, 0, stream>>>(
        qk_hi, qk_lo, f_hi, f_lo, lg, nullptr,
        N, D, (long)C * D, (long)N * D, (long)C * N, 0.03608439182435161f);

    normmax_cols<<<dim3(N / 64, B), 256, 0, stream>>>(lg, mask);
    attn_finish<<<B * C, 256, 0, stream>>>(lg, out_attn, ab16, inv);

    // P[b] = diag(inv) * attn_b @ f_b   [64 x 768], K=1024  (last reader of f_hi)
    gemm_nt<64, 128, 1, 4><<<dim3(D / 128, 1, B), 256, 0, stream>>>(
        ab16, f_hi, Pbf, inv, D, N, (long)C * N, (long)N * D, (long)C * D, C);

    // conv2: GRU-path weights into dead f_hi zone
    f2b_kernel<<<(3 * D * D) / 1024, 256, 0, stream>>>(Wih, Wihb, 3 * D * D);
    f2b_kernel<<<(3 * D * D) / 1024, 256, 0, stream>>>(Whh, Whhb, 3 * D * D);
    f2b_kernel<<<(B * C * D) / 1024, 256, 0, stream>>>(slots, slb, B * C * D);
    f2b_kernel<<<(D * D) / 1024, 256, 0, stream>>>(Wv, Wvb, D * D);

    // upd = P @ Wv^T   [2048 x 768]
    gemm_bt<64, 128, 1, 4, false><<<dim3(D / 128, (B * C) / 64, 1), 256, 0, stream>>>(
        Pbf, Wvb, updb, D, D, 0, 0, 0, 1.f);
    // gi = upd @ W_ih^T   [2048 x 2304] f32
    gemm_bt<128, 128, 2, 2, true><<<dim3(3 * D / 128, (B * C) / 128, 1), 256, 0, stream>>>(
        updb, Wihb, gi, 3 * D, D, 0, 0, 0, 1.f);
    // gh = slots_init @ W_hh^T   [2048 x 2304] f32
    gemm_bt<128, 128, 2, 2, true><<<dim3(3 * D / 128, (B * C) / 128, 1), 256, 0, stream>>>(
        slb, Whhb, gh, 3 * D, D, 0, 0, 0, 1.f);

    gru_gates<<<(B * C * D) / 256, 256, 0, stream>>>(gi, gh, bih, bhh, slots, out_slots);
}

// Round 10
// 298.935 us; speedup vs baseline: 1.2531x; 1.2531x over previous
//
#include <hip/hip_runtime.h>
#include <cstdint>
#include <cmath>

#define DEVINL __device__ __forceinline__

using f32x4  = __attribute__((ext_vector_type(4))) float;
using bf16x8 = __attribute__((ext_vector_type(8))) __bf16;
using u16x8  = __attribute__((ext_vector_type(8))) unsigned short;
using u16x4  = __attribute__((ext_vector_type(4))) unsigned short;
using fl4    = __attribute__((ext_vector_type(4))) float;

DEVINL float bf2f(unsigned short h) {
    unsigned int u = ((unsigned int)h) << 16;
    float f; __builtin_memcpy(&f, &u, 4); return f;
}
DEVINL unsigned short f2bf(float f) {
    unsigned int u; __builtin_memcpy(&u, &f, 4);
    u += 0x7FFFu + ((u >> 16) & 1u);   // RNE
    return (unsigned short)(u >> 16);
}
DEVINL float sqrt_raw(float x) {
    float r; asm("v_sqrt_f32 %0, %1" : "=v"(r) : "v"(x)); return r;
}

DEVINL void gload_lds16(const unsigned short* g, unsigned short* l) {
    __builtin_amdgcn_global_load_lds(
        (__attribute__((address_space(1))) void*)g,
        (__attribute__((address_space(3))) void*)l,
        16, 0, 0);
}

// ---------------------------------------------------------------------------
// f32 -> bf16 elementwise
__global__ __launch_bounds__(256)
void f2b_kernel(const float* __restrict__ x, unsigned short* __restrict__ y, int n)
{
    const int i = (blockIdx.x * 256 + threadIdx.x) * 4;
    if (i < n) {
        fl4 v = *(const fl4*)(x + i);
        u16x4 o;
#pragma unroll
        for (int j = 0; j < 4; ++j) o[j] = f2bf(v[j]);
        *(u16x4*)(y + i) = o;
    }
}

// f32 -> split hi/lo bf16
__global__ __launch_bounds__(256)
void f2b_split(const float* __restrict__ x, unsigned short* __restrict__ yh,
               unsigned short* __restrict__ yl, int n)
{
    const int i = (blockIdx.x * 256 + threadIdx.x) * 4;
    if (i < n) {
        fl4 v = *(const fl4*)(x + i);
        u16x4 oh, ol;
#pragma unroll
        for (int j = 0; j < 4; ++j) {
            oh[j] = f2bf(v[j]);
            ol[j] = f2bf(v[j] - bf2f(oh[j]));
        }
        *(u16x4*)(yh + i) = oh;
        *(u16x4*)(yl + i) = ol;
    }
}

// transpose + split: yh/yl[c*R + r] = split(x[r*C + c])
__global__ __launch_bounds__(256)
void tr_f2b_split(const float* __restrict__ x, unsigned short* __restrict__ yh,
                  unsigned short* __restrict__ yl, int R, int Ccols)
{
    const int o = blockIdx.x * 256 + threadIdx.x;
    if (o < R * Ccols) {
        const int e = o / R, d = o - e * R;
        const float v = x[d * Ccols + e];
        const unsigned short h = f2bf(v);
        yh[o] = h;
        yl[o] = f2bf(v - bf2f(h));
    }
}

// ---------------------------------------------------------------------------
// Split-bf16 3-pass GEMM: C = alpha * (Ah+Al)[M,K] @ (Bh+Bl)[N,K]^T
// OUTMODE 0: f32 out (out1). OUTMODE 1: split bf16 out (out1=hi, out2=lo).
template<int BM, int BN, int WAVES_M, int WAVES_N, int OUTMODE>
__global__ __launch_bounds__(256)
void gemm_bt3(const unsigned short* __restrict__ Ah, const unsigned short* __restrict__ Al,
              const unsigned short* __restrict__ Bh, const unsigned short* __restrict__ Bl,
              void* __restrict__ out1, unsigned short* __restrict__ out2,
              int N, int K, long sA, long sB, long sC, float alpha)
{
    constexpr int BK = 32;
    constexpr int WM = BM / WAVES_M, WN = BN / WAVES_N;
    constexpr int MT = WM / 16, NT = WN / 16;
    __shared__ alignas(16) unsigned short Ash[BM * BK], Asl[BM * BK];
    __shared__ alignas(16) unsigned short Bsh[BN * BK], Bsl[BN * BK];

    const int bz = blockIdx.z;
    Ah += (long)bz * sA; Al += (long)bz * sA;
    Bh += (long)bz * sB; Bl += (long)bz * sB;
    const int row0 = blockIdx.y * BM, col0 = blockIdx.x * BN;
    const int tid = threadIdx.x, l = tid & 63, w = tid >> 6;
    const int wm = w / WAVES_N, wn = w % WAVES_N;
    const int fr = l & 15, fq = l >> 4;

    f32x4 acc[MT][NT] = {};
    constexpr int ACALLS = (BM * BK) / (256 * 8);
    constexpr int BCALLS = (BN * BK) / (256 * 8);

    for (int kt = 0; kt < K; kt += BK) {
#pragma unroll
        for (int c = 0; c < ACALLS; ++c) {
            const int e = (c * 256 + tid) * 8;
            const long g = (long)(row0 + (e >> 5)) * K + kt + (e & 31);
            gload_lds16(Ah + g, &Ash[e]);
            gload_lds16(Al + g, &Asl[e]);
        }
#pragma unroll
        for (int c = 0; c < BCALLS; ++c) {
            const int e = (c * 256 + tid) * 8;
            const long g = (long)(col0 + (e >> 5)) * K + kt + (e & 31);
            gload_lds16(Bh + g, &Bsh[e]);
            gload_lds16(Bl + g, &Bsl[e]);
        }
        __syncthreads();

        bf16x8 afh[MT], afl[MT], bfh[NT], bfl[NT];
#pragma unroll
        for (int m = 0; m < MT; ++m) {
            const int o = (wm * WM + m * 16 + fr) * BK + fq * 8;
            afh[m] = __builtin_bit_cast(bf16x8, *(const u16x8*)&Ash[o]);
            afl[m] = __builtin_bit_cast(bf16x8, *(const u16x8*)&Asl[o]);
        }
#pragma unroll
        for (int n = 0; n < NT; ++n) {
            const int o = (wn * WN + n * 16 + fr) * BK + fq * 8;
            bfh[n] = __builtin_bit_cast(bf16x8, *(const u16x8*)&Bsh[o]);
            bfl[n] = __builtin_bit_cast(bf16x8, *(const u16x8*)&Bsl[o]);
        }
#pragma unroll
        for (int m = 0; m < MT; ++m)
#pragma unroll
            for (int n = 0; n < NT; ++n) {
                acc[m][n] = __builtin_amdgcn_mfma_f32_16x16x32_bf16(afh[m], bfh[n], acc[m][n], 0, 0, 0);
                acc[m][n] = __builtin_amdgcn_mfma_f32_16x16x32_bf16(afh[m], bfl[n], acc[m][n], 0, 0, 0);
                acc[m][n] = __builtin_amdgcn_mfma_f32_16x16x32_bf16(afl[m], bfh[n], acc[m][n], 0, 0, 0);
            }
        __syncthreads();
    }

#pragma unroll
    for (int m = 0; m < MT; ++m) {
        const int gr = row0 + wm * WM + m * 16 + fq * 4;
#pragma unroll
        for (int n = 0; n < NT; ++n) {
            const int gc = col0 + wn * WN + n * 16 + fr;
#pragma unroll
            for (int j = 0; j < 4; ++j) {
                const float v = acc[m][n][j] * alpha;
                const long idx = (long)bz * sC + (long)(gr + j) * N + gc;
                if (OUTMODE == 0) {
                    ((float*)out1)[idx] = v;
                } else {
                    const unsigned short h = f2bf(v);
                    ((unsigned short*)out1)[idx] = h;
                    out2[idx] = f2bf(v - bf2f(h));
                }
            }
        }
    }
}

// ---------------------------------------------------------------------------
// Plain bf16 GEMM: C[M,N] = alpha * A[M,K] @ B[N,K]^T
template<int BM, int BN, int WAVES_M, int WAVES_N, bool OUT_F32>
__global__ __launch_bounds__(256)
void gemm_bt(const unsigned short* __restrict__ A,
             const unsigned short* __restrict__ B,
             void* __restrict__ Cv,
             int N, int K, long sA, long sB, long sC, float alpha)
{
    constexpr int BK = 32;
    constexpr int WM = BM / WAVES_M, WN = BN / WAVES_N;
    constexpr int MT = WM / 16, NT = WN / 16;
    __shared__ alignas(16) unsigned short As[BM * BK];
    __shared__ alignas(16) unsigned short Bs[BN * BK];

    const int bz = blockIdx.z;
    A += (long)bz * sA;
    B += (long)bz * sB;
    const int row0 = blockIdx.y * BM, col0 = blockIdx.x * BN;
    const int tid = threadIdx.x, l = tid & 63, w = tid >> 6;
    const int wm = w / WAVES_N, wn = w % WAVES_N;
    const int fr = l & 15, fq = l >> 4;

    f32x4 acc[MT][NT] = {};
    constexpr int ACALLS = (BM * BK) / (256 * 8);
    constexpr int BCALLS = (BN * BK) / (256 * 8);

    for (int kt = 0; kt < K; kt += BK) {
#pragma unroll
        for (int c = 0; c < ACALLS; ++c) {
            const int e = (c * 256 + tid) * 8;
            gload_lds16(A + (long)(row0 + (e >> 5)) * K + kt + (e & 31), &As[e]);
        }
#pragma unroll
        for (int c = 0; c < BCALLS; ++c) {
            const int e = (c * 256 + tid) * 8;
            gload_lds16(B + (long)(col0 + (e >> 5)) * K + kt + (e & 31), &Bs[e]);
        }
        __syncthreads();

        bf16x8 af[MT], bfr[NT];
#pragma unroll
        for (int m = 0; m < MT; ++m)
            af[m] = __builtin_bit_cast(bf16x8, *(const u16x8*)&As[(wm * WM + m * 16 + fr) * BK + fq * 8]);
#pragma unroll
        for (int n = 0; n < NT; ++n)
            bfr[n] = __builtin_bit_cast(bf16x8, *(const u16x8*)&Bs[(wn * WN + n * 16 + fr) * BK + fq * 8]);
#pragma unroll
        for (int m = 0; m < MT; ++m)
#pragma unroll
            for (int n = 0; n < NT; ++n)
                acc[m][n] = __builtin_amdgcn_mfma_f32_16x16x32_bf16(af[m], bfr[n], acc[m][n], 0, 0, 0);
        __syncthreads();
    }

#pragma unroll
    for (int m = 0; m < MT; ++m) {
        const int gr = row0 + wm * WM + m * 16 + fq * 4;
#pragma unroll
        for (int n = 0; n < NT; ++n) {
            const int gc = col0 + wn * WN + n * 16 + fr;
#pragma unroll
            for (int j = 0; j < 4; ++j) {
                const float v = acc[m][n][j] * alpha;
                if (OUT_F32) ((float*)Cv)[(long)bz * sC + (long)(gr + j) * N + gc] = v;
                else ((unsigned short*)Cv)[(long)bz * sC + (long)(gr + j) * N + gc] = f2bf(v);
            }
        }
    }
}

// ---------------------------------------------------------------------------
// C[M,N] = rowscale(row) * A[M,K] @ B[K,N]   (bf16; B row-major [K x N]).
template<int BM, int BN, int WAVES_M, int WAVES_N>
__global__ __launch_bounds__(256)
void gemm_nt(const unsigned short* __restrict__ A,
             const unsigned short* __restrict__ Bm,
             unsigned short* __restrict__ C,
             const float* __restrict__ rowscale,
             int N, int K, long sA, long sB, long sC, int rsS)
{
    constexpr int BK = 32;
    constexpr int WM = BM / WAVES_M, WN = BN / WAVES_N;
    constexpr int MT = WM / 16, NT = WN / 16;
    __shared__ alignas(16) unsigned short As[BM * BK];
    __shared__ alignas(16) unsigned short Bs[BN * BK];   // Bs[col*BK + k]

    const int bz = blockIdx.z;
    A += (long)bz * sA;
    Bm += (long)bz * sB;
    const int row0 = blockIdx.y * BM, col0 = blockIdx.x * BN;
    const int tid = threadIdx.x, l = tid & 63, w = tid >> 6;
    const int wm = w / WAVES_N, wn = w % WAVES_N;
    const int fr = l & 15, fq = l >> 4;

    f32x4 acc[MT][NT] = {};
    constexpr int ACALLS = (BM * BK) / (256 * 8);
    constexpr int TPR = BN / 8;
    constexpr int RPP = 256 / TPR;
    const int br = tid / TPR, bc8 = (tid % TPR) * 8;

    for (int kt = 0; kt < K; kt += BK) {
#pragma unroll
        for (int c = 0; c < ACALLS; ++c) {
            const int e = (c * 256 + tid) * 8;
            gload_lds16(A + (long)(row0 + (e >> 5)) * K + kt + (e & 31), &As[e]);
        }
#pragma unroll
        for (int p = 0; p < BK / RPP; ++p) {
            const int r = p * RPP + br;
            u16x8 vv = *(const u16x8*)(Bm + (long)(kt + r) * N + col0 + bc8);
#pragma unroll
            for (int j = 0; j < 8; ++j) Bs[(bc8 + j) * BK + r] = vv[j];
        }
        __syncthreads();

        bf16x8 af[MT], bfr[NT];
#pragma unroll
        for (int m = 0; m < MT; ++m)
            af[m] = __builtin_bit_cast(bf16x8, *(const u16x8*)&As[(wm * WM + m * 16 + fr) * BK + fq * 8]);
#pragma unroll
        for (int n = 0; n < NT; ++n)
            bfr[n] = __builtin_bit_cast(bf16x8, *(const u16x8*)&Bs[(wn * WN + n * 16 + fr) * BK + fq * 8]);
#pragma unroll
        for (int m = 0; m < MT; ++m)
#pragma unroll
            for (int n = 0; n < NT; ++n)
                acc[m][n] = __builtin_amdgcn_mfma_f32_16x16x32_bf16(af[m], bfr[n], acc[m][n], 0, 0, 0);
        __syncthreads();
    }

#pragma unroll
    for (int m = 0; m < MT; ++m) {
        const int gr = row0 + wm * WM + m * 16 + fq * 4;
#pragma unroll
        for (int n = 0; n < NT; ++n) {
            const int gc = col0 + wn * WN + n * 16 + fr;
#pragma unroll
            for (int j = 0; j < 4; ++j) {
                float v = acc[m][n][j];
                if (rowscale) v *= rowscale[(long)bz * rsS + gr + j];
                C[(long)bz * sC + (long)(gr + j) * N + gc] = f2bf(v);
            }
        }
    }
}

// ---------------------------------------------------------------------------
// LayerNorm over D=768, f32 in -> split hi/lo bf16 out.
__global__ __launch_bounds__(256)
void ln_rows_split(const float* __restrict__ x,
                   const float* __restrict__ gamma,
                   const float* __restrict__ beta,
                   unsigned short* __restrict__ yh,
                   unsigned short* __restrict__ yl)
{
    constexpr int D = 768;
    const long row = blockIdx.x;
    const int tid = threadIdx.x;
    const float* xr = x + row * D;
    float v[8]; float s = 0.f, s2 = 0.f;
    const bool act = tid < (D / 8);
    if (act) {
        fl4 a = *(const fl4*)(xr + tid * 8);
        fl4 b = *(const fl4*)(xr + tid * 8 + 4);
#pragma unroll
        for (int j = 0; j < 4; ++j) { v[j] = a[j]; v[4 + j] = b[j]; }
#pragma unroll
        for (int j = 0; j < 8; ++j) { s += v[j]; s2 += v[j] * v[j]; }
    }
#pragma unroll
    for (int o = 32; o; o >>= 1) { s += __shfl_down(s, o); s2 += __shfl_down(s2, o); }
    __shared__ float rs[4], rs2[4];
    if ((tid & 63) == 0) { rs[tid >> 6] = s; rs2[tid >> 6] = s2; }
    __syncthreads();
    const float st  = rs[0] + rs[1] + rs[2] + rs[3];
    const float s2t = rs2[0] + rs2[1] + rs2[2] + rs2[3];
    const float mu  = st / (float)D;
    const float var = s2t / (float)D - mu * mu;
    const float r   = rsqrtf(var + 1e-5f);
    if (act) {
        fl4 g1 = *(const fl4*)(gamma + tid * 8), g2 = *(const fl4*)(gamma + tid * 8 + 4);
        fl4 b1 = *(const fl4*)(beta + tid * 8),  b2 = *(const fl4*)(beta + tid * 8 + 4);
        u16x8 oh, ol;
#pragma unroll
        for (int j = 0; j < 8; ++j) {
            const float g = (j < 4) ? g1[j] : g2[j - 4];
            const float bb = (j < 4) ? b1[j] : b2[j - 4];
            const float y = (v[j] - mu) * r * g + bb;
            oh[j] = f2bf(y);
            ol[j] = f2bf(y - bf2f(oh[j]));
        }
        *(u16x8*)(yh + row * D + tid * 8) = oh;
        *(u16x8*)(yl + row * D + tid * 8) = ol;
    }
}

// ---------------------------------------------------------------------------
// normmax (alpha=5) over C=64 slots per (b,n) column; in-place logits->attn f32.
// 34 bisections (bit-identical to reference's 50: f32 bisection stagnates once
// bracket < ulp, ~iter 26); raw v_sqrt for u^(1/4) (±1 ulp).
__global__ __launch_bounds__(256)
void normmax_cols(float* __restrict__ logits, const int* __restrict__ mask)
{
    constexpr int N = 1024, C = 64;
    const int b = blockIdx.y;
    const int tid = threadIdx.x, l = tid & 63, w = tid >> 6;
    const int n = blockIdx.x * 64 + w * 16 + (l & 15);
    const int cb = (l >> 4) * 16;
    float* Lb = logits + (long)b * C * N + n;
    const int m = mask[b * N + n];

    float z[16];
#pragma unroll
    for (int i = 0; i < 16; ++i) z[i] = m ? Lb[(cb + i) * N] : 0.f;

    float mx = z[0];
#pragma unroll
    for (int i = 1; i < 16; ++i) mx = fmaxf(mx, z[i]);
    mx = fmaxf(mx, __shfl_xor(mx, 16));
    mx = fmaxf(mx, __shfl_xor(mx, 32));

    float lo = mx - 1.f, hi = mx;
    for (int it = 0; it < 34; ++it) {
        const float tau = 0.5f * (lo + hi);
        float f = 0.f;
#pragma unroll
        for (int i = 0; i < 16; ++i) {
            const float u = fmaxf(z[i] - tau, 0.f);
            f += u * sqrt_raw(sqrt_raw(u));       // u^(5/4)
        }
        f += __shfl_xor(f, 16);
        f += __shfl_xor(f, 32);
        if (f >= 1.f) lo = tau; else hi = tau;
    }
    const float tau = 0.5f * (lo + hi);
    float sv[16]; float ss = 0.f;
#pragma unroll
    for (int i = 0; i < 16; ++i) {
        const float u = fmaxf(z[i] - tau, 0.f);
        sv[i] = sqrt_raw(sqrt_raw(u));            // u^(1/4)
        ss += sv[i];
    }
    ss += __shfl_xor(ss, 16);
    ss += __shfl_xor(ss, 32);
    const float inv = 1.f / ss;
#pragma unroll
    for (int i = 0; i < 16; ++i) Lb[(cb + i) * N] = m ? sv[i] * inv : 0.f;
}

// ---------------------------------------------------------------------------
// Per (b,c) row: f32 attn to d_out, bf16 copy for P-gemm, invsum.
__global__ __launch_bounds__(256)
void attn_finish(const float* __restrict__ attn,
                 float* __restrict__ attn_out_f32,
                 unsigned short* __restrict__ attn_b16,
                 float* __restrict__ invsum)
{
    constexpr int N = 1024;
    const long row = blockIdx.x;
    const int tid = threadIdx.x;
    const fl4 v = *(const fl4*)(attn + row * N + tid * 4);
    float s = v[0] + v[1] + v[2] + v[3];
#pragma unroll
    for (int o = 32; o; o >>= 1) s += __shfl_down(s, o);
    __shared__ float rs[4];
    if ((tid & 63) == 0) rs[tid >> 6] = s;
    __syncthreads();
    const float tot = rs[0] + rs[1] + rs[2] + rs[3];
    if (tid == 0) invsum[row] = 1.f / (tot + 1e-8f);
    u16x4 o1;
#pragma unroll
    for (int j = 0; j < 4; ++j) o1[j] = f2bf(v[j]);
    *(fl4*)(attn_out_f32 + row * N + tid * 4) = v;
    *(u16x4*)(attn_b16 + row * N + tid * 4) = o1;
}

// ---------------------------------------------------------------------------
// torch GRUCell gates (r,z,n order), h_new = (1-z)*n + z*h. f32 in/out.
__global__ __launch_bounds__(256)
void gru_gates(const float* __restrict__ gi, const float* __restrict__ gh,
               const float* __restrict__ b_ih, const float* __restrict__ b_hh,
               const float* __restrict__ h, float* __restrict__ out)
{
    constexpr int D = 768;
    const int idx = blockIdx.x * 256 + threadIdx.x;
    const int row = idx / D, d = idx - row * D;
    const float* gir = gi + (long)row * 3 * D;
    const float* ghr = gh + (long)row * 3 * D;
    const float ir  = gir[d]         + b_ih[d];
    const float iz  = gir[D + d]     + b_ih[D + d];
    const float in_ = gir[2 * D + d] + b_ih[2 * D + d];
    const float hr  = ghr[d]         + b_hh[d];
    const float hz  = ghr[D + d]     + b_hh[D + d];
    const float hn  = ghr[2 * D + d] + b_hh[2 * D + d];
    const float r   = 1.f / (1.f + expf(-(ir + hr)));
    const float zg  = 1.f / (1.f + expf(-(iz + hz)));
    const float ng  = tanhf(in_ + r * hn);
    out[idx] = (1.f - zg) * ng + zg * h[idx];
}

extern "C" void kernel_launch(void* const* d_in, const int* in_sizes, int n_in,
                              void* d_out, int out_size, void* d_ws, size_t ws_size,
                              hipStream_t stream)
{
    const float* features = (const float*)d_in[0];
    const float* slots    = (const float*)d_in[1];
    const int*   mask     = (const int*)d_in[2];
    const float* lnf_g = (const float*)d_in[3];
    const float* lnf_b = (const float*)d_in[4];
    const float* lns_g = (const float*)d_in[5];
    const float* lns_b = (const float*)d_in[6];
    const float* Wk  = (const float*)d_in[7];
    const float* Wv  = (const float*)d_in[8];
    const float* Wq  = (const float*)d_in[9];
    const float* Wih = (const float*)d_in[10];
    const float* Whh = (const float*)d_in[11];
    const float* bih = (const float*)d_in[12];
    const float* bhh = (const float*)d_in[13];

    constexpr int B = 32, N = 1024, C = 64, D = 768;
    char* ws = (char*)d_ws;
    // ---- workspace layout, peak 132.7 MB (round-8 layout)
    unsigned short* f_hi = (unsigned short*)(ws + 0);          // 50,331,648
    float*          gi   = (float*)(ws + 0);                   // [gi gemm .. gru]
    float*          gh   = (float*)(ws + 18874368);            // [gh gemm .. gru]
    unsigned short* Wihb = (unsigned short*)(ws + 37748736);   // [conv2 .. gi gemm]
    unsigned short* Whhb = (unsigned short*)(ws + 41287680);   // [conv2 .. gh gemm]
    unsigned short* slb  = (unsigned short*)(ws + 44826624);   // [conv2 .. gh gemm]
    unsigned short* Wvb  = (unsigned short*)(ws + 47972352);   // [conv2 .. upd gemm]
    unsigned short* f_lo = (unsigned short*)(ws + 50331648);   // 50,331,648
    unsigned short* ab16 = (unsigned short*)(ws + 50331648);   // [attn_finish .. P gemm]
    unsigned short* Pbf  = (unsigned short*)(ws + 54525952);   // [P gemm .. upd gemm]
    unsigned short* updb = (unsigned short*)(ws + 57671680);   // [upd gemm .. gi gemm]
    float*          lg    = (float*)(ws + 100663296);          //  8,388,608
    float*          inv   = (float*)(ws + 109051904);          //      8,192
    unsigned short* s_hi  = (unsigned short*)(ws + 109060096); //  3,145,728
    unsigned short* s_lo  = (unsigned short*)(ws + 112205824);
    unsigned short* q_hi  = (unsigned short*)(ws + 115351552);
    unsigned short* q_lo  = (unsigned short*)(ws + 118497280);
    unsigned short* qk_hi = (unsigned short*)(ws + 121643008);
    unsigned short* qk_lo = (unsigned short*)(ws + 124788736);
    unsigned short* Wq_hi = (unsigned short*)(ws + 127934464); //  1,179,648
    unsigned short* Wq_lo = (unsigned short*)(ws + 129114112);
    unsigned short* WkT_hi= (unsigned short*)(ws + 130293760);
    unsigned short* WkT_lo= (unsigned short*)(ws + 131473408); // ends 132,653,056

    float* out_slots = (float*)d_out;
    float* out_attn  = out_slots + (long)B * C * D;

    // conv1: logits-path weights (split)
    f2b_split<<<(D * D) / 1024, 256, 0, stream>>>(Wq, Wq_hi, Wq_lo, D * D);
    tr_f2b_split<<<(D * D + 255) / 256, 256, 0, stream>>>(Wk, WkT_hi, WkT_lo, D, D);

    ln_rows_split<<<B * N, 256, 0, stream>>>(features, lnf_g, lnf_b, f_hi, f_lo);
    ln_rows_split<<<B * C, 256, 0, stream>>>(slots, lns_g, lns_b, s_hi, s_lo);

    // q = s @ Wq^T   [2048 x 768], split out
    gemm_bt3<64, 128, 1, 4, 1><<<dim3(D / 128, (B * C) / 64, 1), 256, 0, stream>>>(
        s_hi, s_lo, Wq_hi, Wq_lo, q_hi, q_lo, D, D, 0, 0, 0, 1.f);
    // qk = q @ (WkT)^T   [2048 x 768], split out
    gemm_bt3<64, 128, 1, 4, 1><<<dim3(D / 128, (B * C) / 64, 1), 256, 0, stream>>>(
        q_hi, q_lo, WkT_hi, WkT_lo, qk_hi, qk_lo, D, D, 0, 0, 0, 1.f);
    // logits[b] = qk_b @ f_b^T / sqrt(768)   [64 x 1024] f32
    gemm_bt3<64, 128, 1, 4, 0><<<dim3(N / 128, 1, B), 256, 0, stream>>>(
        qk_hi, qk_lo, f_hi, f_lo, lg, nullptr,
        N, D, (long)C * D, (long)N * D, (long)C * N, 0.03608439182435161f);

    normmax_cols<<<dim3(N / 64, B), 256, 0, stream>>>(lg, mask);
    attn_finish<<<B * C, 256, 0, stream>>>(lg, out_attn, ab16, inv);

    // P[b] = diag(inv) * attn_b @ f_b   [64 x 768], K=1024  (last reader of f_hi)
    gemm_nt<64, 128, 1, 4><<<dim3(D / 128, 1, B), 256, 0, stream>>>(
        ab16, f_hi, Pbf, inv, D, N, (long)C * N, (long)N * D, (long)C * D, C);

    // conv2: GRU-path weights into dead f_hi zone
    f2b_kernel<<<(3 * D * D) / 1024, 256, 0, stream>>>(Wih, Wihb, 3 * D * D);
    f2b_kernel<<<(3 * D * D) / 1024, 256, 0, stream>>>(Whh, Whhb, 3 * D * D);
    f2b_kernel<<<(B * C * D) / 1024, 256, 0, stream>>>(slots, slb, B * C * D);
    f2b_kernel<<<(D * D) / 1024, 256, 0, stream>>>(Wv, Wvb, D * D);

    // upd = P @ Wv^T   [2048 x 768]
    gemm_bt<64, 128, 1, 4, false><<<dim3(D / 128, (B * C) / 64, 1), 256, 0, stream>>>(
        Pbf, Wvb, updb, D, D, 0, 0, 0, 1.f);
    // gi = upd @ W_ih^T   [2048 x 2304] f32
    gemm_bt<128, 128, 2, 2, true><<<dim3(3 * D / 128, (B * C) / 128, 1), 256, 0, stream>>>(
        updb, Wihb, gi, 3 * D, D, 0, 0, 0, 1.f);
    // gh = slots_init @ W_hh^T   [2048 x 2304] f32
    gemm_bt<128, 128, 2, 2, true><<<dim3(3 * D / 128, (B * C) / 128, 1), 256, 0, stream>>>(
        slb, Whhb, gh, 3 * D, D, 0, 0, 0, 1.f);

    gru_gates<<<(B * C * D) / 256, 256, 0, stream>>>(gi, gh, bih, bhh, slots, out_slots);
}

// Round 11
// 288.405 us; speedup vs baseline: 1.2989x; 1.0365x over previous
//
#include <hip/hip_runtime.h>
#include <cstdint>
#include <cmath>

#define DEVINL __device__ __forceinline__

using f32x4  = __attribute__((ext_vector_type(4))) float;
using bf16x8 = __attribute__((ext_vector_type(8))) __bf16;
using u16x8  = __attribute__((ext_vector_type(8))) unsigned short;
using u16x4  = __attribute__((ext_vector_type(4))) unsigned short;
using fl4    = __attribute__((ext_vector_type(4))) float;

DEVINL float bf2f(unsigned short h) {
    unsigned int u = ((unsigned int)h) << 16;
    float f; __builtin_memcpy(&f, &u, 4); return f;
}
DEVINL unsigned short f2bf(float f) {
    unsigned int u; __builtin_memcpy(&u, &f, 4);
    u += 0x7FFFu + ((u >> 16) & 1u);   // RNE
    return (unsigned short)(u >> 16);
}
DEVINL float sqrt_raw(float x) {
    float r; asm("v_sqrt_f32 %0, %1" : "=v"(r) : "v"(x)); return r;
}

DEVINL void gload_lds16(const unsigned short* g, unsigned short* l) {
    __builtin_amdgcn_global_load_lds(
        (__attribute__((address_space(1))) void*)g,
        (__attribute__((address_space(3))) void*)l,
        16, 0, 0);
}

// ---------------------------------------------------------------------------
// transpose + split: yh/yl[c*R + r] = split(x[r*C + c])
__global__ __launch_bounds__(256)
void tr_f2b_split(const float* __restrict__ x, unsigned short* __restrict__ yh,
                  unsigned short* __restrict__ yl, int R, int Ccols)
{
    const int o = blockIdx.x * 256 + threadIdx.x;
    if (o < R * Ccols) {
        const int e = o / R, d = o - e * R;
        const float v = x[d * Ccols + e];
        const unsigned short h = f2bf(v);
        yh[o] = h;
        yl[o] = f2bf(v - bf2f(h));
    }
}

// ---------------------------------------------------------------------------
// Fused GRU-path conversions: Wih, Whh, slots, Wv -> bf16 (one launch)
__global__ __launch_bounds__(256)
void conv2_fused(const float* __restrict__ Wih, const float* __restrict__ Whh,
                 const float* __restrict__ sl,  const float* __restrict__ Wv,
                 unsigned short* __restrict__ Wihb, unsigned short* __restrict__ Whhb,
                 unsigned short* __restrict__ slb,  unsigned short* __restrict__ Wvb)
{
    constexpr int S1 = 3 * 768 * 768;            // Wih
    constexpr int S2 = S1 + 3 * 768 * 768;       // +Whh
    constexpr int S3 = S2 + 32 * 64 * 768;       // +slots
    constexpr int S4 = S3 + 768 * 768;           // +Wv
    const int i = (blockIdx.x * 256 + threadIdx.x) * 4;
    if (i >= S4) return;
    const float* src; unsigned short* dst; int off;
    if (i < S1)      { src = Wih; dst = Wihb; off = i; }
    else if (i < S2) { src = Whh; dst = Whhb; off = i - S1; }
    else if (i < S3) { src = sl;  dst = slb;  off = i - S2; }
    else             { src = Wv;  dst = Wvb;  off = i - S3; }
    fl4 v = *(const fl4*)(src + off);
    u16x4 o;
#pragma unroll
    for (int j = 0; j < 4; ++j) o[j] = f2bf(v[j]);
    *(u16x4*)(dst + off) = o;
}

// ---------------------------------------------------------------------------
// Split-bf16 3-pass GEMM: C = alpha * (Ah+Al)[M,K] @ (Bh+Bl)[N,K]^T
// OUTMODE 0: f32 out (out1). OUTMODE 1: split bf16 out (out1=hi, out2=lo).
template<int BM, int BN, int WAVES_M, int WAVES_N, int OUTMODE>
__global__ __launch_bounds__(256)
void gemm_bt3(const unsigned short* __restrict__ Ah, const unsigned short* __restrict__ Al,
              const unsigned short* __restrict__ Bh, const unsigned short* __restrict__ Bl,
              void* __restrict__ out1, unsigned short* __restrict__ out2,
              int N, int K, long sA, long sB, long sC, float alpha)
{
    constexpr int BK = 32;
    constexpr int WM = BM / WAVES_M, WN = BN / WAVES_N;
    constexpr int MT = WM / 16, NT = WN / 16;
    __shared__ alignas(16) unsigned short Ash[BM * BK], Asl[BM * BK];
    __shared__ alignas(16) unsigned short Bsh[BN * BK], Bsl[BN * BK];

    const int bz = blockIdx.z;
    Ah += (long)bz * sA; Al += (long)bz * sA;
    Bh += (long)bz * sB; Bl += (long)bz * sB;
    const int row0 = blockIdx.y * BM, col0 = blockIdx.x * BN;
    const int tid = threadIdx.x, l = tid & 63, w = tid >> 6;
    const int wm = w / WAVES_N, wn = w % WAVES_N;
    const int fr = l & 15, fq = l >> 4;

    f32x4 acc[MT][NT] = {};
    constexpr int ACALLS = (BM * BK) / (256 * 8);
    constexpr int BCALLS = (BN * BK) / (256 * 8);

    for (int kt = 0; kt < K; kt += BK) {
#pragma unroll
        for (int c = 0; c < ACALLS; ++c) {
            const int e = (c * 256 + tid) * 8;
            const long g = (long)(row0 + (e >> 5)) * K + kt + (e & 31);
            gload_lds16(Ah + g, &Ash[e]);
            gload_lds16(Al + g, &Asl[e]);
        }
#pragma unroll
        for (int c = 0; c < BCALLS; ++c) {
            const int e = (c * 256 + tid) * 8;
            const long g = (long)(col0 + (e >> 5)) * K + kt + (e & 31);
            gload_lds16(Bh + g, &Bsh[e]);
            gload_lds16(Bl + g, &Bsl[e]);
        }
        __syncthreads();

        bf16x8 afh[MT], afl[MT], bfh[NT], bfl[NT];
#pragma unroll
        for (int m = 0; m < MT; ++m) {
            const int o = (wm * WM + m * 16 + fr) * BK + fq * 8;
            afh[m] = __builtin_bit_cast(bf16x8, *(const u16x8*)&Ash[o]);
            afl[m] = __builtin_bit_cast(bf16x8, *(const u16x8*)&Asl[o]);
        }
#pragma unroll
        for (int n = 0; n < NT; ++n) {
            const int o = (wn * WN + n * 16 + fr) * BK + fq * 8;
            bfh[n] = __builtin_bit_cast(bf16x8, *(const u16x8*)&Bsh[o]);
            bfl[n] = __builtin_bit_cast(bf16x8, *(const u16x8*)&Bsl[o]);
        }
#pragma unroll
        for (int m = 0; m < MT; ++m)
#pragma unroll
            for (int n = 0; n < NT; ++n) {
                acc[m][n] = __builtin_amdgcn_mfma_f32_16x16x32_bf16(afh[m], bfh[n], acc[m][n], 0, 0, 0);
                acc[m][n] = __builtin_amdgcn_mfma_f32_16x16x32_bf16(afh[m], bfl[n], acc[m][n], 0, 0, 0);
                acc[m][n] = __builtin_amdgcn_mfma_f32_16x16x32_bf16(afl[m], bfh[n], acc[m][n], 0, 0, 0);
            }
        __syncthreads();
    }

#pragma unroll
    for (int m = 0; m < MT; ++m) {
        const int gr = row0 + wm * WM + m * 16 + fq * 4;
#pragma unroll
        for (int n = 0; n < NT; ++n) {
            const int gc = col0 + wn * WN + n * 16 + fr;
#pragma unroll
            for (int j = 0; j < 4; ++j) {
                const float v = acc[m][n][j] * alpha;
                const long idx = (long)bz * sC + (long)(gr + j) * N + gc;
                if (OUTMODE == 0) {
                    ((float*)out1)[idx] = v;
                } else {
                    const unsigned short h = f2bf(v);
                    ((unsigned short*)out1)[idx] = h;
                    out2[idx] = f2bf(v - bf2f(h));
                }
            }
        }
    }
}

// ---------------------------------------------------------------------------
// Plain bf16 GEMM: C[M,N] = alpha * A[M,K] @ B[N,K]^T
template<int BM, int BN, int WAVES_M, int WAVES_N, bool OUT_F32>
__global__ __launch_bounds__(256)
void gemm_bt(const unsigned short* __restrict__ A,
             const unsigned short* __restrict__ B,
             void* __restrict__ Cv,
             int N, int K, long sA, long sB, long sC, float alpha)
{
    constexpr int BK = 32;
    constexpr int WM = BM / WAVES_M, WN = BN / WAVES_N;
    constexpr int MT = WM / 16, NT = WN / 16;
    __shared__ alignas(16) unsigned short As[BM * BK];
    __shared__ alignas(16) unsigned short Bs[BN * BK];

    const int bz = blockIdx.z;
    A += (long)bz * sA;
    B += (long)bz * sB;
    const int row0 = blockIdx.y * BM, col0 = blockIdx.x * BN;
    const int tid = threadIdx.x, l = tid & 63, w = tid >> 6;
    const int wm = w / WAVES_N, wn = w % WAVES_N;
    const int fr = l & 15, fq = l >> 4;

    f32x4 acc[MT][NT] = {};
    constexpr int ACALLS = (BM * BK) / (256 * 8);
    constexpr int BCALLS = (BN * BK) / (256 * 8);

    for (int kt = 0; kt < K; kt += BK) {
#pragma unroll
        for (int c = 0; c < ACALLS; ++c) {
            const int e = (c * 256 + tid) * 8;
            gload_lds16(A + (long)(row0 + (e >> 5)) * K + kt + (e & 31), &As[e]);
        }
#pragma unroll
        for (int c = 0; c < BCALLS; ++c) {
            const int e = (c * 256 + tid) * 8;
            gload_lds16(B + (long)(col0 + (e >> 5)) * K + kt + (e & 31), &Bs[e]);
        }
        __syncthreads();

        bf16x8 af[MT], bfr[NT];
#pragma unroll
        for (int m = 0; m < MT; ++m)
            af[m] = __builtin_bit_cast(bf16x8, *(const u16x8*)&As[(wm * WM + m * 16 + fr) * BK + fq * 8]);
#pragma unroll
        for (int n = 0; n < NT; ++n)
            bfr[n] = __builtin_bit_cast(bf16x8, *(const u16x8*)&Bs[(wn * WN + n * 16 + fr) * BK + fq * 8]);
#pragma unroll
        for (int m = 0; m < MT; ++m)
#pragma unroll
            for (int n = 0; n < NT; ++n)
                acc[m][n] = __builtin_amdgcn_mfma_f32_16x16x32_bf16(af[m], bfr[n], acc[m][n], 0, 0, 0);
        __syncthreads();
    }

#pragma unroll
    for (int m = 0; m < MT; ++m) {
        const int gr = row0 + wm * WM + m * 16 + fq * 4;
#pragma unroll
        for (int n = 0; n < NT; ++n) {
            const int gc = col0 + wn * WN + n * 16 + fr;
#pragma unroll
            for (int j = 0; j < 4; ++j) {
                const float v = acc[m][n][j] * alpha;
                if (OUT_F32) ((float*)Cv)[(long)bz * sC + (long)(gr + j) * N + gc] = v;
                else ((unsigned short*)Cv)[(long)bz * sC + (long)(gr + j) * N + gc] = f2bf(v);
            }
        }
    }
}

// ---------------------------------------------------------------------------
// P GEMM with fused row-sum normalization:
// C[M,N] = (1/(rowsum(A)+eps)) * A[M,K] @ B[K,N]  (bf16; B row-major [K x N]).
template<int BM, int BN, int WAVES_M, int WAVES_N>
__global__ __launch_bounds__(256)
void gemm_nt_rs(const unsigned short* __restrict__ A,
                const unsigned short* __restrict__ Bm,
                unsigned short* __restrict__ C,
                int N, int K, long sA, long sB, long sC)
{
    constexpr int BK = 32;
    constexpr int WM = BM / WAVES_M, WN = BN / WAVES_N;
    constexpr int MT = WM / 16, NT = WN / 16;
    __shared__ alignas(16) unsigned short As[BM * BK];
    __shared__ alignas(16) unsigned short Bs[BN * BK];   // Bs[col*BK + k]
    __shared__ float rsums[BM];

    const int bz = blockIdx.z;
    A += (long)bz * sA;
    Bm += (long)bz * sB;
    const int row0 = blockIdx.y * BM, col0 = blockIdx.x * BN;
    const int tid = threadIdx.x, l = tid & 63, w = tid >> 6;
    const int wm = w / WAVES_N, wn = w % WAVES_N;
    const int fr = l & 15, fq = l >> 4;

    f32x4 acc[MT][NT] = {};
    float rsum = 0.f;
    constexpr int ACALLS = (BM * BK) / (256 * 8);
    constexpr int TPR = BN / 8;
    constexpr int RPP = 256 / TPR;
    const int br = tid / TPR, bc8 = (tid % TPR) * 8;

    for (int kt = 0; kt < K; kt += BK) {
#pragma unroll
        for (int c = 0; c < ACALLS; ++c) {
            const int e = (c * 256 + tid) * 8;
            gload_lds16(A + (long)(row0 + (e >> 5)) * K + kt + (e & 31), &As[e]);
        }
#pragma unroll
        for (int p = 0; p < BK / RPP; ++p) {
            const int r = p * RPP + br;
            u16x8 vv = *(const u16x8*)(Bm + (long)(kt + r) * N + col0 + bc8);
#pragma unroll
            for (int j = 0; j < 8; ++j) Bs[(bc8 + j) * BK + r] = vv[j];
        }
        __syncthreads();

        if (tid < BM) {
#pragma unroll
            for (int kk = 0; kk < BK / 8; ++kk) {
                u16x8 vv = *(const u16x8*)&As[tid * BK + kk * 8];
#pragma unroll
                for (int j = 0; j < 8; ++j) rsum += bf2f(vv[j]);
            }
        }

        bf16x8 af[MT], bfr[NT];
#pragma unroll
        for (int m = 0; m < MT; ++m)
            af[m] = __builtin_bit_cast(bf16x8, *(const u16x8*)&As[(wm * WM + m * 16 + fr) * BK + fq * 8]);
#pragma unroll
        for (int n = 0; n < NT; ++n)
            bfr[n] = __builtin_bit_cast(bf16x8, *(const u16x8*)&Bs[(wn * WN + n * 16 + fr) * BK + fq * 8]);
#pragma unroll
        for (int m = 0; m < MT; ++m)
#pragma unroll
            for (int n = 0; n < NT; ++n)
                acc[m][n] = __builtin_amdgcn_mfma_f32_16x16x32_bf16(af[m], bfr[n], acc[m][n], 0, 0, 0);
        __syncthreads();
    }

    if (tid < BM) rsums[tid] = rsum;
    __syncthreads();

#pragma unroll
    for (int m = 0; m < MT; ++m) {
        const int lr = wm * WM + m * 16 + fq * 4;
        const int gr = row0 + lr;
#pragma unroll
        for (int n = 0; n < NT; ++n) {
            const int gc = col0 + wn * WN + n * 16 + fr;
#pragma unroll
            for (int j = 0; j < 4; ++j) {
                const float inv = 1.f / (rsums[lr + j] + 1e-8f);
                C[(long)bz * sC + (long)(gr + j) * N + gc] = f2bf(acc[m][n][j] * inv);
            }
        }
    }
}

// ---------------------------------------------------------------------------
// LayerNorm over D=768, f32 in -> split hi/lo bf16 out.
__global__ __launch_bounds__(256)
void ln_rows_split(const float* __restrict__ x,
                   const float* __restrict__ gamma,
                   const float* __restrict__ beta,
                   unsigned short* __restrict__ yh,
                   unsigned short* __restrict__ yl)
{
    constexpr int D = 768;
    const long row = blockIdx.x;
    const int tid = threadIdx.x;
    const float* xr = x + row * D;
    float v[8]; float s = 0.f, s2 = 0.f;
    const bool act = tid < (D / 8);
    if (act) {
        fl4 a = *(const fl4*)(xr + tid * 8);
        fl4 b = *(const fl4*)(xr + tid * 8 + 4);
#pragma unroll
        for (int j = 0; j < 4; ++j) { v[j] = a[j]; v[4 + j] = b[j]; }
#pragma unroll
        for (int j = 0; j < 8; ++j) { s += v[j]; s2 += v[j] * v[j]; }
    }
#pragma unroll
    for (int o = 32; o; o >>= 1) { s += __shfl_down(s, o); s2 += __shfl_down(s2, o); }
    __shared__ float rs[4], rs2[4];
    if ((tid & 63) == 0) { rs[tid >> 6] = s; rs2[tid >> 6] = s2; }
    __syncthreads();
    const float st  = rs[0] + rs[1] + rs[2] + rs[3];
    const float s2t = rs2[0] + rs2[1] + rs2[2] + rs2[3];
    const float mu  = st / (float)D;
    const float var = s2t / (float)D - mu * mu;
    const float r   = rsqrtf(var + 1e-5f);
    if (act) {
        fl4 g1 = *(const fl4*)(gamma + tid * 8), g2 = *(const fl4*)(gamma + tid * 8 + 4);
        fl4 b1 = *(const fl4*)(beta + tid * 8),  b2 = *(const fl4*)(beta + tid * 8 + 4);
        u16x8 oh, ol;
#pragma unroll
        for (int j = 0; j < 8; ++j) {
            const float g = (j < 4) ? g1[j] : g2[j - 4];
            const float bb = (j < 4) ? b1[j] : b2[j - 4];
            const float y = (v[j] - mu) * r * g + bb;
            oh[j] = f2bf(y);
            ol[j] = f2bf(y - bf2f(oh[j]));
        }
        *(u16x8*)(yh + row * D + tid * 8) = oh;
        *(u16x8*)(yl + row * D + tid * 8) = ol;
    }
}

// ---------------------------------------------------------------------------
// normmax (alpha=5) over C=64 slots per (b,n) column.
// 34 bisections (== reference's 50 in f32), raw v_sqrt for u^(1/4).
// Writes f32 attn to d_out and bf16 copy for the P gemm.
__global__ __launch_bounds__(256)
void normmax_cols(const float* __restrict__ logits, const int* __restrict__ mask,
                  float* __restrict__ attn_f32, unsigned short* __restrict__ attn_b16)
{
    constexpr int N = 1024, C = 64;
    const int b = blockIdx.y;
    const int tid = threadIdx.x, l = tid & 63, w = tid >> 6;
    const int n = blockIdx.x * 64 + w * 16 + (l & 15);
    const int cb = (l >> 4) * 16;
    const long base = (long)b * C * N + n;
    const float* Lb = logits + base;
    const int m = mask[b * N + n];

    float z[16];
#pragma unroll
    for (int i = 0; i < 16; ++i) z[i] = m ? Lb[(cb + i) * N] : 0.f;

    float mx = z[0];
#pragma unroll
    for (int i = 1; i < 16; ++i) mx = fmaxf(mx, z[i]);
    mx = fmaxf(mx, __shfl_xor(mx, 16));
    mx = fmaxf(mx, __shfl_xor(mx, 32));

    float lo = mx - 1.f, hi = mx;
    for (int it = 0; it < 34; ++it) {
        const float tau = 0.5f * (lo + hi);
        float f = 0.f;
#pragma unroll
        for (int i = 0; i < 16; ++i) {
            const float u = fmaxf(z[i] - tau, 0.f);
            f += u * sqrt_raw(sqrt_raw(u));       // u^(5/4)
        }
        f += __shfl_xor(f, 16);
        f += __shfl_xor(f, 32);
        if (f >= 1.f) lo = tau; else hi = tau;
    }
    const float tau = 0.5f * (lo + hi);
    float sv[16]; float ss = 0.f;
#pragma unroll
    for (int i = 0; i < 16; ++i) {
        const float u = fmaxf(z[i] - tau, 0.f);
        sv[i] = sqrt_raw(sqrt_raw(u));            // u^(1/4)
        ss += sv[i];
    }
    ss += __shfl_xor(ss, 16);
    ss += __shfl_xor(ss, 32);
    const float inv = 1.f / ss;
#pragma unroll
    for (int i = 0; i < 16; ++i) {
        const float a = m ? sv[i] * inv : 0.f;
        attn_f32[base + (long)(cb + i) * N] = a;
        attn_b16[base + (long)(cb + i) * N] = f2bf(a);
    }
}

// ---------------------------------------------------------------------------
// torch GRUCell gates (r,z,n order), h_new = (1-z)*n + z*h. f32 in/out.
__global__ __launch_bounds__(256)
void gru_gates(const float* __restrict__ gi, const float* __restrict__ gh,
               const float* __restrict__ b_ih, const float* __restrict__ b_hh,
               const float* __restrict__ h, float* __restrict__ out)
{
    constexpr int D = 768;
    const int idx = blockIdx.x * 256 + threadIdx.x;
    const int row = idx / D, d = idx - row * D;
    const float* gir = gi + (long)row * 3 * D;
    const float* ghr = gh + (long)row * 3 * D;
    const float ir  = gir[d]         + b_ih[d];
    const float iz  = gir[D + d]     + b_ih[D + d];
    const float in_ = gir[2 * D + d] + b_ih[2 * D + d];
    const float hr  = ghr[d]         + b_hh[d];
    const float hz  = ghr[D + d]     + b_hh[D + d];
    const float hn  = ghr[2 * D + d] + b_hh[2 * D + d];
    const float r   = 1.f / (1.f + expf(-(ir + hr)));
    const float zg  = 1.f / (1.f + expf(-(iz + hz)));
    const float ng  = tanhf(in_ + r * hn);
    out[idx] = (1.f - zg) * ng + zg * h[idx];
}

extern "C" void kernel_launch(void* const* d_in, const int* in_sizes, int n_in,
                              void* d_out, int out_size, void* d_ws, size_t ws_size,
                              hipStream_t stream)
{
    const float* features = (const float*)d_in[0];
    const float* slots    = (const float*)d_in[1];
    const int*   mask     = (const int*)d_in[2];
    const float* lnf_g = (const float*)d_in[3];
    const float* lnf_b = (const float*)d_in[4];
    const float* lns_g = (const float*)d_in[5];
    const float* lns_b = (const float*)d_in[6];
    const float* Wk  = (const float*)d_in[7];
    const float* Wv  = (const float*)d_in[8];
    const float* Wq  = (const float*)d_in[9];
    const float* Wih = (const float*)d_in[10];
    const float* Whh = (const float*)d_in[11];
    const float* bih = (const float*)d_in[12];
    const float* bhh = (const float*)d_in[13];

    constexpr int B = 32, N = 1024, C = 64, D = 768;
    char* ws = (char*)d_ws;
    // ---- workspace layout, peak ~128.7 MB
    unsigned short* f_hi = (unsigned short*)(ws + 0);          // [LN .. P gemm] 50,331,648
    float*          gi   = (float*)(ws + 0);                   // [gi gemm .. gru]
    float*          gh   = (float*)(ws + 18874368);            // [gh gemm .. gru]
    unsigned short* Wihb = (unsigned short*)(ws + 37748736);   // [conv2 .. gi gemm]
    unsigned short* Whhb = (unsigned short*)(ws + 41287680);   // [conv2 .. gh gemm]
    unsigned short* slb  = (unsigned short*)(ws + 44826624);   // [conv2 .. gh gemm]
    unsigned short* Wvb  = (unsigned short*)(ws + 47972352);   // [conv2 .. upd gemm]
    unsigned short* f_lo = (unsigned short*)(ws + 50331648);   // [LN .. logits] 50,331,648
    unsigned short* ab16 = (unsigned short*)(ws + 50331648);   // [normmax .. P gemm]
    unsigned short* Pbf  = (unsigned short*)(ws + 54525952);   // [P gemm .. upd gemm]
    unsigned short* updb = (unsigned short*)(ws + 57671680);   // [upd gemm .. gi gemm]
    float*          lg     = (float*)(ws + 100663296);          //  8,388,608
    unsigned short* s_hi   = (unsigned short*)(ws + 109051904); //  3,145,728
    unsigned short* s_lo   = (unsigned short*)(ws + 112197632);
    unsigned short* qk_hi  = (unsigned short*)(ws + 115343360);
    unsigned short* qk_lo  = (unsigned short*)(ws + 118489088);
    unsigned short* WqT_hi = (unsigned short*)(ws + 121634816); //  1,179,648
    unsigned short* WqT_lo = (unsigned short*)(ws + 122814464);
    unsigned short* WkT_hi = (unsigned short*)(ws + 123994112);
    unsigned short* WkT_lo = (unsigned short*)(ws + 125173760);
    unsigned short* MT_hi  = (unsigned short*)(ws + 126353408);
    unsigned short* MT_lo  = (unsigned short*)(ws + 127533056); // ends 128,712,704

    float* out_slots = (float*)d_out;
    float* out_attn  = out_slots + (long)B * C * D;

    // conv1: transpose+split logits-path weights
    tr_f2b_split<<<(D * D + 255) / 256, 256, 0, stream>>>(Wq, WqT_hi, WqT_lo, D, D);
    tr_f2b_split<<<(D * D + 255) / 256, 256, 0, stream>>>(Wk, WkT_hi, WkT_lo, D, D);

    ln_rows_split<<<B * N, 256, 0, stream>>>(features, lnf_g, lnf_b, f_hi, f_lo);
    ln_rows_split<<<B * C, 256, 0, stream>>>(slots, lns_g, lns_b, s_hi, s_lo);

    // M[j,i] = sum_k Wk[k,j]*Wq[k,i]  [768 x 768], split out
    gemm_bt3<64, 128, 1, 4, 1><<<dim3(D / 128, D / 64, 1), 256, 0, stream>>>(
        WkT_hi, WkT_lo, WqT_hi, WqT_lo, MT_hi, MT_lo, D, D, 0, 0, 0, 1.f);
    // qk = s @ M^T   [2048 x 768], split out   (qk[r,j] = sum_i s[r,i] M[j,i])
    gemm_bt3<64, 128, 1, 4, 1><<<dim3(D / 128, (B * C) / 64, 1), 256, 0, stream>>>(
        s_hi, s_lo, MT_hi, MT_lo, qk_hi, qk_lo, D, D, 0, 0, 0, 1.f);
    // logits[b] = qk_b @ f_b^T / sqrt(768)   [64 x 1024] f32
    gemm_bt3<64, 128, 1, 4, 0><<<dim3(N / 128, 1, B), 256, 0, stream>>>(
        qk_hi, qk_lo, f_hi, f_lo, lg, nullptr,
        N, D, (long)C * D, (long)N * D, (long)C * N, 0.03608439182435161f);

    // normmax -> f32 attn (d_out) + bf16 copy
    normmax_cols<<<dim3(N / 64, B), 256, 0, stream>>>(lg, mask, out_attn, ab16);

    // P[b] = diag(1/(rowsum+eps)) * attn_b @ f_b   [64 x 768], K=1024
    gemm_nt_rs<64, 128, 1, 4><<<dim3(D / 128, 1, B), 256, 0, stream>>>(
        ab16, f_hi, Pbf, D, N, (long)C * N, (long)N * D, (long)C * D);

    // conv2: fused GRU-path conversions into dead f_hi zone
    {
        constexpr int TOT = 3 * D * D + 3 * D * D + B * C * D + D * D;
        conv2_fused<<<(TOT / 4 + 255) / 256, 256, 0, stream>>>(
            Wih, Whh, slots, Wv, Wihb, Whhb, slb, Wvb);
    }

    // upd = P @ Wv^T   [2048 x 768]
    gemm_bt<64, 128, 1, 4, false><<<dim3(D / 128, (B * C) / 64, 1), 256, 0, stream>>>(
        Pbf, Wvb, updb, D, D, 0, 0, 0, 1.f);
    // gi = upd @ W_ih^T   [2048 x 2304] f32
    gemm_bt<128, 128, 2, 2, true><<<dim3(3 * D / 128, (B * C) / 128, 1), 256, 0, stream>>>(
        updb, Wihb, gi, 3 * D, D, 0, 0, 0, 1.f);
    // gh = slots_init @ W_hh^T   [2048 x 2304] f32
    gemm_bt<128, 128, 2, 2, true><<<dim3(3 * D / 128, (B * C) / 128, 1), 256, 0, stream>>>(
        slb, Whhb, gh, 3 * D, D, 0, 0, 0, 1.f);

    gru_gates<<<(B * C * D) / 256, 256, 0, stream>>>(gi, gh, bih, bhh, slots, out_slots);
}

// Round 12
// 232.397 us; speedup vs baseline: 1.6119x; 1.2410x over previous
//
#include <hip/hip_runtime.h>
#include <cstdint>
#include <cmath>

#define DEVINL __device__ __forceinline__

using f32x4  = __attribute__((ext_vector_type(4))) float;
using bf16x8 = __attribute__((ext_vector_type(8))) __bf16;
using u16x8  = __attribute__((ext_vector_type(8))) unsigned short;
using u16x4  = __attribute__((ext_vector_type(4))) unsigned short;
using fl4    = __attribute__((ext_vector_type(4))) float;

DEVINL float bf2f(unsigned short h) {
    unsigned int u = ((unsigned int)h) << 16;
    float f; __builtin_memcpy(&f, &u, 4); return f;
}
DEVINL unsigned short f2bf(float f) {
    unsigned int u; __builtin_memcpy(&u, &f, 4);
    u += 0x7FFFu + ((u >> 16) & 1u);   // RNE
    return (unsigned short)(u >> 16);
}
DEVINL float sqrt_raw(float x) {
    float r; asm("v_sqrt_f32 %0, %1" : "=v"(r) : "v"(x)); return r;
}

DEVINL void gload_lds16(const unsigned short* g, unsigned short* l) {
    __builtin_amdgcn_global_load_lds(
        (__attribute__((address_space(1))) void*)g,
        (__attribute__((address_space(3))) void*)l,
        16, 0, 0);
}

// ---------------------------------------------------------------------------
// Fused transpose+split of Wq and Wk: yh/yl[c*768 + r] = split(x[r*768 + c])
__global__ __launch_bounds__(256)
void tr2_f2b_split(const float* __restrict__ Wq, const float* __restrict__ Wk,
                   unsigned short* __restrict__ WqT_hi, unsigned short* __restrict__ WqT_lo,
                   unsigned short* __restrict__ WkT_hi, unsigned short* __restrict__ WkT_lo)
{
    constexpr int S = 768 * 768;
    const int o = blockIdx.x * 256 + threadIdx.x;
    if (o >= 2 * S) return;
    const float* x; unsigned short *yh, *yl; int i;
    if (o < S) { x = Wq; yh = WqT_hi; yl = WqT_lo; i = o; }
    else       { x = Wk; yh = WkT_hi; yl = WkT_lo; i = o - S; }
    const int e = i / 768, d = i - e * 768;
    const float v = x[d * 768 + e];
    const unsigned short h = f2bf(v);
    yh[i] = h;
    yl[i] = f2bf(v - bf2f(h));
}

// ---------------------------------------------------------------------------
// Fused GRU-path conversions: Wih, Whh, slots, Wv -> bf16 (one launch)
__global__ __launch_bounds__(256)
void conv2_fused(const float* __restrict__ Wih, const float* __restrict__ Whh,
                 const float* __restrict__ sl,  const float* __restrict__ Wv,
                 unsigned short* __restrict__ Wihb, unsigned short* __restrict__ Whhb,
                 unsigned short* __restrict__ slb,  unsigned short* __restrict__ Wvb)
{
    constexpr int S1 = 3 * 768 * 768;
    constexpr int S2 = S1 + 3 * 768 * 768;
    constexpr int S3 = S2 + 32 * 64 * 768;
    constexpr int S4 = S3 + 768 * 768;
    const int i = (blockIdx.x * 256 + threadIdx.x) * 4;
    if (i >= S4) return;
    const float* src; unsigned short* dst; int off;
    if (i < S1)      { src = Wih; dst = Wihb; off = i; }
    else if (i < S2) { src = Whh; dst = Whhb; off = i - S1; }
    else if (i < S3) { src = sl;  dst = slb;  off = i - S2; }
    else             { src = Wv;  dst = Wvb;  off = i - S3; }
    fl4 v = *(const fl4*)(src + off);
    u16x4 o;
#pragma unroll
    for (int j = 0; j < 4; ++j) o[j] = f2bf(v[j]);
    *(u16x4*)(dst + off) = o;
}

// ---------------------------------------------------------------------------
// Split-bf16 3-pass GEMM: C = alpha * (Ah+Al)[M,K] @ (Bh+Bl)[N,K]^T
// OUTMODE 0: f32 out (out1). OUTMODE 1: split bf16 out (out1=hi, out2=lo).
template<int BM, int BN, int WAVES_M, int WAVES_N, int OUTMODE>
__global__ __launch_bounds__(256)
void gemm_bt3(const unsigned short* __restrict__ Ah, const unsigned short* __restrict__ Al,
              const unsigned short* __restrict__ Bh, const unsigned short* __restrict__ Bl,
              void* __restrict__ out1, unsigned short* __restrict__ out2,
              int N, int K, long sA, long sB, long sC, float alpha)
{
    constexpr int BK = 32;
    constexpr int WM = BM / WAVES_M, WN = BN / WAVES_N;
    constexpr int MT = WM / 16, NT = WN / 16;
    __shared__ alignas(16) unsigned short Ash[BM * BK], Asl[BM * BK];
    __shared__ alignas(16) unsigned short Bsh[BN * BK], Bsl[BN * BK];

    const int bz = blockIdx.z;
    Ah += (long)bz * sA; Al += (long)bz * sA;
    Bh += (long)bz * sB; Bl += (long)bz * sB;
    const int row0 = blockIdx.y * BM, col0 = blockIdx.x * BN;
    const int tid = threadIdx.x, l = tid & 63, w = tid >> 6;
    const int wm = w / WAVES_N, wn = w % WAVES_N;
    const int fr = l & 15, fq = l >> 4;

    f32x4 acc[MT][NT] = {};
    constexpr int ACALLS = (BM * BK) / (256 * 8);
    constexpr int BCALLS = (BN * BK) / (256 * 8);

    for (int kt = 0; kt < K; kt += BK) {
#pragma unroll
        for (int c = 0; c < ACALLS; ++c) {
            const int e = (c * 256 + tid) * 8;
            const long g = (long)(row0 + (e >> 5)) * K + kt + (e & 31);
            gload_lds16(Ah + g, &Ash[e]);
            gload_lds16(Al + g, &Asl[e]);
        }
#pragma unroll
        for (int c = 0; c < BCALLS; ++c) {
            const int e = (c * 256 + tid) * 8;
            const long g = (long)(col0 + (e >> 5)) * K + kt + (e & 31);
            gload_lds16(Bh + g, &Bsh[e]);
            gload_lds16(Bl + g, &Bsl[e]);
        }
        __syncthreads();

        bf16x8 afh[MT], afl[MT], bfh[NT], bfl[NT];
#pragma unroll
        for (int m = 0; m < MT; ++m) {
            const int o = (wm * WM + m * 16 + fr) * BK + fq * 8;
            afh[m] = __builtin_bit_cast(bf16x8, *(const u16x8*)&Ash[o]);
            afl[m] = __builtin_bit_cast(bf16x8, *(const u16x8*)&Asl[o]);
        }
#pragma unroll
        for (int n = 0; n < NT; ++n) {
            const int o = (wn * WN + n * 16 + fr) * BK + fq * 8;
            bfh[n] = __builtin_bit_cast(bf16x8, *(const u16x8*)&Bsh[o]);
            bfl[n] = __builtin_bit_cast(bf16x8, *(const u16x8*)&Bsl[o]);
        }
#pragma unroll
        for (int m = 0; m < MT; ++m)
#pragma unroll
            for (int n = 0; n < NT; ++n) {
                acc[m][n] = __builtin_amdgcn_mfma_f32_16x16x32_bf16(afh[m], bfh[n], acc[m][n], 0, 0, 0);
                acc[m][n] = __builtin_amdgcn_mfma_f32_16x16x32_bf16(afh[m], bfl[n], acc[m][n], 0, 0, 0);
                acc[m][n] = __builtin_amdgcn_mfma_f32_16x16x32_bf16(afl[m], bfh[n], acc[m][n], 0, 0, 0);
            }
        __syncthreads();
    }

#pragma unroll
    for (int m = 0; m < MT; ++m) {
        const int gr = row0 + wm * WM + m * 16 + fq * 4;
#pragma unroll
        for (int n = 0; n < NT; ++n) {
            const int gc = col0 + wn * WN + n * 16 + fr;
#pragma unroll
            for (int j = 0; j < 4; ++j) {
                const float v = acc[m][n][j] * alpha;
                const long idx = (long)bz * sC + (long)(gr + j) * N + gc;
                if (OUTMODE == 0) {
                    ((float*)out1)[idx] = v;
                } else {
                    const unsigned short h = f2bf(v);
                    ((unsigned short*)out1)[idx] = h;
                    out2[idx] = f2bf(v - bf2f(h));
                }
            }
        }
    }
}

// ---------------------------------------------------------------------------
// Plain bf16 GEMM: C[M,N] = alpha * A[M,K] @ B[N,K]^T  (batched via blockIdx.z)
template<int BM, int BN, int WAVES_M, int WAVES_N, bool OUT_F32>
__global__ __launch_bounds__(256)
void gemm_bt(const unsigned short* __restrict__ A,
             const unsigned short* __restrict__ B,
             void* __restrict__ Cv,
             int N, int K, long sA, long sB, long sC, float alpha)
{
    constexpr int BK = 32;
    constexpr int WM = BM / WAVES_M, WN = BN / WAVES_N;
    constexpr int MT = WM / 16, NT = WN / 16;
    __shared__ alignas(16) unsigned short As[BM * BK];
    __shared__ alignas(16) unsigned short Bs[BN * BK];

    const int bz = blockIdx.z;
    A += (long)bz * sA;
    B += (long)bz * sB;
    const int row0 = blockIdx.y * BM, col0 = blockIdx.x * BN;
    const int tid = threadIdx.x, l = tid & 63, w = tid >> 6;
    const int wm = w / WAVES_N, wn = w % WAVES_N;
    const int fr = l & 15, fq = l >> 4;

    f32x4 acc[MT][NT] = {};
    constexpr int ACALLS = (BM * BK) / (256 * 8);
    constexpr int BCALLS = (BN * BK) / (256 * 8);

    for (int kt = 0; kt < K; kt += BK) {
#pragma unroll
        for (int c = 0; c < ACALLS; ++c) {
            const int e = (c * 256 + tid) * 8;
            gload_lds16(A + (long)(row0 + (e >> 5)) * K + kt + (e & 31), &As[e]);
        }
#pragma unroll
        for (int c = 0; c < BCALLS; ++c) {
            const int e = (c * 256 + tid) * 8;
            gload_lds16(B + (long)(col0 + (e >> 5)) * K + kt + (e & 31), &Bs[e]);
        }
        __syncthreads();

        bf16x8 af[MT], bfr[NT];
#pragma unroll
        for (int m = 0; m < MT; ++m)
            af[m] = __builtin_bit_cast(bf16x8, *(const u16x8*)&As[(wm * WM + m * 16 + fr) * BK + fq * 8]);
#pragma unroll
        for (int n = 0; n < NT; ++n)
            bfr[n] = __builtin_bit_cast(bf16x8, *(const u16x8*)&Bs[(wn * WN + n * 16 + fr) * BK + fq * 8]);
#pragma unroll
        for (int m = 0; m < MT; ++m)
#pragma unroll
            for (int n = 0; n < NT; ++n)
                acc[m][n] = __builtin_amdgcn_mfma_f32_16x16x32_bf16(af[m], bfr[n], acc[m][n], 0, 0, 0);
        __syncthreads();
    }

#pragma unroll
    for (int m = 0; m < MT; ++m) {
        const int gr = row0 + wm * WM + m * 16 + fq * 4;
#pragma unroll
        for (int n = 0; n < NT; ++n) {
            const int gc = col0 + wn * WN + n * 16 + fr;
#pragma unroll
            for (int j = 0; j < 4; ++j) {
                const float v = acc[m][n][j] * alpha;
                if (OUT_F32) ((float*)Cv)[(long)bz * sC + (long)(gr + j) * N + gc] = v;
                else ((unsigned short*)Cv)[(long)bz * sC + (long)(gr + j) * N + gc] = f2bf(v);
            }
        }
    }
}

// ---------------------------------------------------------------------------
// P GEMM with fused row-sum normalization:
// C[M,N] = (1/(rowsum(A)+eps)) * A[M,K] @ B[K,N]  (bf16; B row-major [K x N]).
template<int BM, int BN, int WAVES_M, int WAVES_N>
__global__ __launch_bounds__(256)
void gemm_nt_rs(const unsigned short* __restrict__ A,
                const unsigned short* __restrict__ Bm,
                unsigned short* __restrict__ C,
                int N, int K, long sA, long sB, long sC)
{
    constexpr int BK = 32;
    constexpr int WM = BM / WAVES_M, WN = BN / WAVES_N;
    constexpr int MT = WM / 16, NT = WN / 16;
    __shared__ alignas(16) unsigned short As[BM * BK];
    __shared__ alignas(16) unsigned short Bs[BN * BK];   // Bs[col*BK + k]
    __shared__ float rsums[BM];

    const int bz = blockIdx.z;
    A += (long)bz * sA;
    Bm += (long)bz * sB;
    const int row0 = blockIdx.y * BM, col0 = blockIdx.x * BN;
    const int tid = threadIdx.x, l = tid & 63, w = tid >> 6;
    const int wm = w / WAVES_N, wn = w % WAVES_N;
    const int fr = l & 15, fq = l >> 4;

    f32x4 acc[MT][NT] = {};
    float rsum = 0.f;
    constexpr int ACALLS = (BM * BK) / (256 * 8);
    constexpr int TPR = BN / 8;
    constexpr int RPP = 256 / TPR;
    const int br = tid / TPR, bc8 = (tid % TPR) * 8;

    for (int kt = 0; kt < K; kt += BK) {
#pragma unroll
        for (int c = 0; c < ACALLS; ++c) {
            const int e = (c * 256 + tid) * 8;
            gload_lds16(A + (long)(row0 + (e >> 5)) * K + kt + (e & 31), &As[e]);
        }
#pragma unroll
        for (int p = 0; p < BK / RPP; ++p) {
            const int r = p * RPP + br;
            u16x8 vv = *(const u16x8*)(Bm + (long)(kt + r) * N + col0 + bc8);
#pragma unroll
            for (int j = 0; j < 8; ++j) Bs[(bc8 + j) * BK + r] = vv[j];
        }
        __syncthreads();

        if (tid < BM) {
#pragma unroll
            for (int kk = 0; kk < BK / 8; ++kk) {
                u16x8 vv = *(const u16x8*)&As[tid * BK + kk * 8];
#pragma unroll
                for (int j = 0; j < 8; ++j) rsum += bf2f(vv[j]);
            }
        }

        bf16x8 af[MT], bfr[NT];
#pragma unroll
        for (int m = 0; m < MT; ++m)
            af[m] = __builtin_bit_cast(bf16x8, *(const u16x8*)&As[(wm * WM + m * 16 + fr) * BK + fq * 8]);
#pragma unroll
        for (int n = 0; n < NT; ++n)
            bfr[n] = __builtin_bit_cast(bf16x8, *(const u16x8*)&Bs[(wn * WN + n * 16 + fr) * BK + fq * 8]);
#pragma unroll
        for (int m = 0; m < MT; ++m)
#pragma unroll
            for (int n = 0; n < NT; ++n)
                acc[m][n] = __builtin_amdgcn_mfma_f32_16x16x32_bf16(af[m], bfr[n], acc[m][n], 0, 0, 0);
        __syncthreads();
    }

    if (tid < BM) rsums[tid] = rsum;
    __syncthreads();

#pragma unroll
    for (int m = 0; m < MT; ++m) {
        const int lr = wm * WM + m * 16 + fq * 4;
        const int gr = row0 + lr;
#pragma unroll
        for (int n = 0; n < NT; ++n) {
            const int gc = col0 + wn * WN + n * 16 + fr;
#pragma unroll
            for (int j = 0; j < 4; ++j) {
                const float inv = 1.f / (rsums[lr + j] + 1e-8f);
                C[(long)bz * sC + (long)(gr + j) * N + gc] = f2bf(acc[m][n][j] * inv);
            }
        }
    }
}

// ---------------------------------------------------------------------------
// LayerNorm over D=768, f32 in -> split hi/lo bf16 out.
// One wave per row (lane handles 12 elems), 4 rows per block. No LDS.
__global__ __launch_bounds__(256)
void ln_rows_split(const float* __restrict__ x,
                   const float* __restrict__ gamma,
                   const float* __restrict__ beta,
                   unsigned short* __restrict__ yh,
                   unsigned short* __restrict__ yl)
{
    constexpr int D = 768;
    const int lane = threadIdx.x & 63;
    const long row = (long)blockIdx.x * 4 + (threadIdx.x >> 6);
    const float* xr = x + row * D + lane * 12;
    fl4 a = *(const fl4*)xr;
    fl4 b = *(const fl4*)(xr + 4);
    fl4 c = *(const fl4*)(xr + 8);
    float v[12];
#pragma unroll
    for (int j = 0; j < 4; ++j) { v[j] = a[j]; v[4 + j] = b[j]; v[8 + j] = c[j]; }
    float s = 0.f, s2 = 0.f;
#pragma unroll
    for (int j = 0; j < 12; ++j) { s += v[j]; s2 += v[j] * v[j]; }
#pragma unroll
    for (int o = 1; o < 64; o <<= 1) { s += __shfl_xor(s, o); s2 += __shfl_xor(s2, o); }
    const float mu  = s / (float)D;
    const float var = s2 / (float)D - mu * mu;
    const float r   = rsqrtf(var + 1e-5f);

    const float* gp = gamma + lane * 12;
    const float* bp = beta + lane * 12;
    fl4 g0 = *(const fl4*)gp, g1 = *(const fl4*)(gp + 4), g2 = *(const fl4*)(gp + 8);
    fl4 b0 = *(const fl4*)bp, b1 = *(const fl4*)(bp + 4), b2 = *(const fl4*)(bp + 8);
    float gg[12], bb[12];
#pragma unroll
    for (int j = 0; j < 4; ++j) {
        gg[j] = g0[j]; gg[4 + j] = g1[j]; gg[8 + j] = g2[j];
        bb[j] = b0[j]; bb[4 + j] = b1[j]; bb[8 + j] = b2[j];
    }
    unsigned short oh[12], ol[12];
#pragma unroll
    for (int j = 0; j < 12; ++j) {
        const float y = (v[j] - mu) * r * gg[j] + bb[j];
        oh[j] = f2bf(y);
        ol[j] = f2bf(y - bf2f(oh[j]));
    }
    unsigned short* yhp = yh + row * D + lane * 12;
    unsigned short* ylp = yl + row * D + lane * 12;
#pragma unroll
    for (int t = 0; t < 3; ++t) {
        *(u16x4*)(yhp + t * 4) = *(u16x4*)&oh[t * 4];
        *(u16x4*)(ylp + t * 4) = *(u16x4*)&ol[t * 4];
    }
}

// ---------------------------------------------------------------------------
// normmax (alpha=5) over C=64 slots per (b,n) column.
// 34 bisections (== reference's 50 in f32), raw v_sqrt for u^(1/4).
__global__ __launch_bounds__(256)
void normmax_cols(const float* __restrict__ logits, const int* __restrict__ mask,
                  float* __restrict__ attn_f32, unsigned short* __restrict__ attn_b16)
{
    constexpr int N = 1024, C = 64;
    const int b = blockIdx.y;
    const int tid = threadIdx.x, l = tid & 63, w = tid >> 6;
    const int n = blockIdx.x * 64 + w * 16 + (l & 15);
    const int cb = (l >> 4) * 16;
    const long base = (long)b * C * N + n;
    const float* Lb = logits + base;
    const int m = mask[b * N + n];

    float z[16];
#pragma unroll
    for (int i = 0; i < 16; ++i) z[i] = m ? Lb[(cb + i) * N] : 0.f;

    float mx = z[0];
#pragma unroll
    for (int i = 1; i < 16; ++i) mx = fmaxf(mx, z[i]);
    mx = fmaxf(mx, __shfl_xor(mx, 16));
    mx = fmaxf(mx, __shfl_xor(mx, 32));

    float lo = mx - 1.f, hi = mx;
    for (int it = 0; it < 34; ++it) {
        const float tau = 0.5f * (lo + hi);
        float f = 0.f;
#pragma unroll
        for (int i = 0; i < 16; ++i) {
            const float u = fmaxf(z[i] - tau, 0.f);
            f += u * sqrt_raw(sqrt_raw(u));       // u^(5/4)
        }
        f += __shfl_xor(f, 16);
        f += __shfl_xor(f, 32);
        if (f >= 1.f) lo = tau; else hi = tau;
    }
    const float tau = 0.5f * (lo + hi);
    float sv[16]; float ss = 0.f;
#pragma unroll
    for (int i = 0; i < 16; ++i) {
        const float u = fmaxf(z[i] - tau, 0.f);
        sv[i] = sqrt_raw(sqrt_raw(u));            // u^(1/4)
        ss += sv[i];
    }
    ss += __shfl_xor(ss, 16);
    ss += __shfl_xor(ss, 32);
    const float inv = 1.f / ss;
#pragma unroll
    for (int i = 0; i < 16; ++i) {
        const float a = m ? sv[i] * inv : 0.f;
        attn_f32[base + (long)(cb + i) * N] = a;
        attn_b16[base + (long)(cb + i) * N] = f2bf(a);
    }
}

// ---------------------------------------------------------------------------
// torch GRUCell gates (r,z,n order), h_new = (1-z)*n + z*h. f32 in/out, x4 vec.
__global__ __launch_bounds__(256)
void gru_gates(const float* __restrict__ gi, const float* __restrict__ gh,
               const float* __restrict__ b_ih, const float* __restrict__ b_hh,
               const float* __restrict__ h, float* __restrict__ out)
{
    constexpr int D = 768;
    const int t = blockIdx.x * 256 + threadIdx.x;   // [0, 2048*192)
    const int row = t / (D / 4), d = (t - row * (D / 4)) * 4;
    const float* gir = gi + (long)row * 3 * D;
    const float* ghr = gh + (long)row * 3 * D;
    fl4 ir  = *(const fl4*)(gir + d);
    fl4 iz  = *(const fl4*)(gir + D + d);
    fl4 in_ = *(const fl4*)(gir + 2 * D + d);
    fl4 hr  = *(const fl4*)(ghr + d);
    fl4 hz  = *(const fl4*)(ghr + D + d);
    fl4 hn  = *(const fl4*)(ghr + 2 * D + d);
    fl4 bir = *(const fl4*)(b_ih + d);
    fl4 biz = *(const fl4*)(b_ih + D + d);
    fl4 bin = *(const fl4*)(b_ih + 2 * D + d);
    fl4 bhr = *(const fl4*)(b_hh + d);
    fl4 bhz = *(const fl4*)(b_hh + D + d);
    fl4 bhn = *(const fl4*)(b_hh + 2 * D + d);
    fl4 hv  = *(const fl4*)(h + (long)row * D + d);
    fl4 o;
#pragma unroll
    for (int j = 0; j < 4; ++j) {
        const float r  = 1.f / (1.f + expf(-(ir[j] + bir[j] + hr[j] + bhr[j])));
        const float zg = 1.f / (1.f + expf(-(iz[j] + biz[j] + hz[j] + bhz[j])));
        const float ng = tanhf(in_[j] + bin[j] + r * (hn[j] + bhn[j]));
        o[j] = (1.f - zg) * ng + zg * hv[j];
    }
    *(fl4*)(out + (long)row * D + d) = o;
}

extern "C" void kernel_launch(void* const* d_in, const int* in_sizes, int n_in,
                              void* d_out, int out_size, void* d_ws, size_t ws_size,
                              hipStream_t stream)
{
    const float* features = (const float*)d_in[0];
    const float* slots    = (const float*)d_in[1];
    const int*   mask     = (const int*)d_in[2];
    const float* lnf_g = (const float*)d_in[3];
    const float* lnf_b = (const float*)d_in[4];
    const float* lns_g = (const float*)d_in[5];
    const float* lns_b = (const float*)d_in[6];
    const float* Wk  = (const float*)d_in[7];
    const float* Wv  = (const float*)d_in[8];
    const float* Wq  = (const float*)d_in[9];
    const float* Wih = (const float*)d_in[10];
    const float* Whh = (const float*)d_in[11];
    const float* bih = (const float*)d_in[12];
    const float* bhh = (const float*)d_in[13];

    constexpr int B = 32, N = 1024, C = 64, D = 768;
    char* ws = (char*)d_ws;
    // ---- workspace layout, peak ~128.7 MB
    unsigned short* f_hi = (unsigned short*)(ws + 0);          // [LN .. P gemm] 50,331,648
    float*          gi   = (float*)(ws + 0);                   // [gih gemm .. gru]
    float*          gh   = (float*)(ws + 18874368);            // contiguous after gi
    unsigned short* Wihb = (unsigned short*)(ws + 37748736);   // [conv2 .. gih gemm]
    unsigned short* Whhb = (unsigned short*)(ws + 41287680);   // contiguous after Wihb
    unsigned short* Wvb  = (unsigned short*)(ws + 44826624);   // [conv2 .. upd gemm]
    unsigned short* f_lo = (unsigned short*)(ws + 50331648);   // [LN .. logits] 50,331,648
    unsigned short* ab16 = (unsigned short*)(ws + 50331648);   // [normmax .. P gemm]
    unsigned short* Pbf  = (unsigned short*)(ws + 54525952);   // [P gemm .. upd gemm]
    unsigned short* updb = (unsigned short*)(ws + 57671680);   // [upd gemm .. gih gemm]
    unsigned short* slb  = (unsigned short*)(ws + 60817408);   // contiguous after updb
    float*          lg     = (float*)(ws + 100663296);          //  8,388,608
    unsigned short* s_hi   = (unsigned short*)(ws + 109051904); //  3,145,728
    unsigned short* s_lo   = (unsigned short*)(ws + 112197632);
    unsigned short* qk_hi  = (unsigned short*)(ws + 115343360);
    unsigned short* qk_lo  = (unsigned short*)(ws + 118489088);
    unsigned short* WqT_hi = (unsigned short*)(ws + 121634816); //  1,179,648
    unsigned short* WqT_lo = (unsigned short*)(ws + 122814464);
    unsigned short* WkT_hi = (unsigned short*)(ws + 123994112);
    unsigned short* WkT_lo = (unsigned short*)(ws + 125173760);
    unsigned short* MT_hi  = (unsigned short*)(ws + 126353408);
    unsigned short* MT_lo  = (unsigned short*)(ws + 127533056); // ends 128,712,704

    float* out_slots = (float*)d_out;
    float* out_attn  = out_slots + (long)B * C * D;

    // conv1: fused transpose+split of Wq, Wk
    tr2_f2b_split<<<(2 * D * D + 255) / 256, 256, 0, stream>>>(
        Wq, Wk, WqT_hi, WqT_lo, WkT_hi, WkT_lo);

    ln_rows_split<<<(B * N) / 4, 256, 0, stream>>>(features, lnf_g, lnf_b, f_hi, f_lo);
    ln_rows_split<<<(B * C) / 4, 256, 0, stream>>>(slots, lns_g, lns_b, s_hi, s_lo);

    // M[j,i] = sum_k Wk[k,j]*Wq[k,i]  [768 x 768], split out
    gemm_bt3<64, 64, 2, 2, 1><<<dim3(D / 64, D / 64, 1), 256, 0, stream>>>(
        WkT_hi, WkT_lo, WqT_hi, WqT_lo, MT_hi, MT_lo, D, D, 0, 0, 0, 1.f);
    // qk = s @ M^T   [2048 x 768], split out
    gemm_bt3<64, 64, 2, 2, 1><<<dim3(D / 64, (B * C) / 64, 1), 256, 0, stream>>>(
        s_hi, s_lo, MT_hi, MT_lo, qk_hi, qk_lo, D, D, 0, 0, 0, 1.f);
    // logits[b] = qk_b @ f_b^T / sqrt(768)   [64 x 1024] f32
    gemm_bt3<64, 64, 2, 2, 0><<<dim3(N / 64, 1, B), 256, 0, stream>>>(
        qk_hi, qk_lo, f_hi, f_lo, lg, nullptr,
        N, D, (long)C * D, (long)N * D, (long)C * N, 0.03608439182435161f);

    // normmax -> f32 attn (d_out) + bf16 copy
    normmax_cols<<<dim3(N / 64, B), 256, 0, stream>>>(lg, mask, out_attn, ab16);

    // P[b] = diag(1/(rowsum+eps)) * attn_b @ f_b   [64 x 768], K=1024
    gemm_nt_rs<64, 64, 2, 2><<<dim3(D / 64, 1, B), 256, 0, stream>>>(
        ab16, f_hi, Pbf, D, N, (long)C * N, (long)N * D, (long)C * D);

    // conv2: fused GRU-path conversions (into dead f_hi / f_lo zones)
    {
        constexpr int TOT = 3 * D * D + 3 * D * D + B * C * D + D * D;
        conv2_fused<<<(TOT / 4 + 255) / 256, 256, 0, stream>>>(
            Wih, Whh, slots, Wv, Wihb, Whhb, slb, Wvb);
    }

    // upd = P @ Wv^T   [2048 x 768]
    gemm_bt<64, 64, 2, 2, false><<<dim3(D / 64, (B * C) / 64, 1), 256, 0, stream>>>(
        Pbf, Wvb, updb, D, D, 0, 0, 0, 1.f);

    // gi = upd @ W_ih^T ; gh = slots @ W_hh^T  — batched via blockIdx.z
    gemm_bt<128, 128, 2, 2, true><<<dim3(3 * D / 128, (B * C) / 128, 2), 256, 0, stream>>>(
        updb, Wihb, gi, 3 * D, D,
        (long)(B * C) * D, (long)(3 * D) * D, (long)(B * C) * 3 * D, 1.f);

    gru_gates<<<(B * C * D / 4) / 256, 256, 0, stream>>>(gi, gh, bih, bhh, slots, out_slots);
}

// Round 13
// 224.734 us; speedup vs baseline: 1.6668x; 1.0341x over previous
//
#include <hip/hip_runtime.h>
#include <cstdint>
#include <cmath>

#define DEVINL __device__ __forceinline__

using f32x4  = __attribute__((ext_vector_type(4))) float;
using bf16x8 = __attribute__((ext_vector_type(8))) __bf16;
using u16x8  = __attribute__((ext_vector_type(8))) unsigned short;
using u16x4  = __attribute__((ext_vector_type(4))) unsigned short;
using fl4    = __attribute__((ext_vector_type(4))) float;

DEVINL float bf2f(unsigned short h) {
    unsigned int u = ((unsigned int)h) << 16;
    float f; __builtin_memcpy(&f, &u, 4); return f;
}
DEVINL unsigned short f2bf(float f) {
    unsigned int u; __builtin_memcpy(&u, &f, 4);
    u += 0x7FFFu + ((u >> 16) & 1u);   // RNE
    return (unsigned short)(u >> 16);
}
DEVINL float sqrt_raw(float x) {
    float r; asm("v_sqrt_f32 %0, %1" : "=v"(r) : "v"(x)); return r;
}

DEVINL void gload_lds16(const unsigned short* g, unsigned short* l) {
    __builtin_amdgcn_global_load_lds(
        (__attribute__((address_space(1))) void*)g,
        (__attribute__((address_space(3))) void*)l,
        16, 0, 0);
}

// ---------------------------------------------------------------------------
// Fused transpose+split of Wq and Wk: yh/yl[c*768 + r] = split(x[r*768 + c])
__global__ __launch_bounds__(256)
void tr2_f2b_split(const float* __restrict__ Wq, const float* __restrict__ Wk,
                   unsigned short* __restrict__ WqT_hi, unsigned short* __restrict__ WqT_lo,
                   unsigned short* __restrict__ WkT_hi, unsigned short* __restrict__ WkT_lo)
{
    constexpr int S = 768 * 768;
    const int o = blockIdx.x * 256 + threadIdx.x;
    if (o >= 2 * S) return;
    const float* x; unsigned short *yh, *yl; int i;
    if (o < S) { x = Wq; yh = WqT_hi; yl = WqT_lo; i = o; }
    else       { x = Wk; yh = WkT_hi; yl = WkT_lo; i = o - S; }
    const int e = i / 768, d = i - e * 768;
    const float v = x[d * 768 + e];
    const unsigned short h = f2bf(v);
    yh[i] = h;
    yl[i] = f2bf(v - bf2f(h));
}

// ---------------------------------------------------------------------------
// Fused GRU-path conversions: Wih, Whh, slots, Wv -> bf16 (one launch)
__global__ __launch_bounds__(256)
void conv2_fused(const float* __restrict__ Wih, const float* __restrict__ Whh,
                 const float* __restrict__ sl,  const float* __restrict__ Wv,
                 unsigned short* __restrict__ Wihb, unsigned short* __restrict__ Whhb,
                 unsigned short* __restrict__ slb,  unsigned short* __restrict__ Wvb)
{
    constexpr int S1 = 3 * 768 * 768;
    constexpr int S2 = S1 + 3 * 768 * 768;
    constexpr int S3 = S2 + 32 * 64 * 768;
    constexpr int S4 = S3 + 768 * 768;
    const int i = (blockIdx.x * 256 + threadIdx.x) * 4;
    if (i >= S4) return;
    const float* src; unsigned short* dst; int off;
    if (i < S1)      { src = Wih; dst = Wihb; off = i; }
    else if (i < S2) { src = Whh; dst = Whhb; off = i - S1; }
    else if (i < S3) { src = sl;  dst = slb;  off = i - S2; }
    else             { src = Wv;  dst = Wvb;  off = i - S3; }
    fl4 v = *(const fl4*)(src + off);
    u16x4 o;
#pragma unroll
    for (int j = 0; j < 4; ++j) o[j] = f2bf(v[j]);
    *(u16x4*)(dst + off) = o;
}

// ---------------------------------------------------------------------------
// Split-bf16 3-pass GEMM: C = alpha * (Ah+Al)[M,K] @ (Bh+Bl)[N,K]^T
// OUTMODE 0: f32 out (out1). OUTMODE 1: split bf16 out (out1=hi, out2=lo).
template<int BM, int BN, int WAVES_M, int WAVES_N, int OUTMODE>
__global__ __launch_bounds__(256)
void gemm_bt3(const unsigned short* __restrict__ Ah, const unsigned short* __restrict__ Al,
              const unsigned short* __restrict__ Bh, const unsigned short* __restrict__ Bl,
              void* __restrict__ out1, unsigned short* __restrict__ out2,
              int N, int K, long sA, long sB, long sC, float alpha)
{
    constexpr int BK = 32;
    constexpr int WM = BM / WAVES_M, WN = BN / WAVES_N;
    constexpr int MT = WM / 16, NT = WN / 16;
    __shared__ alignas(16) unsigned short Ash[BM * BK], Asl[BM * BK];
    __shared__ alignas(16) unsigned short Bsh[BN * BK], Bsl[BN * BK];

    const int bz = blockIdx.z;
    Ah += (long)bz * sA; Al += (long)bz * sA;
    Bh += (long)bz * sB; Bl += (long)bz * sB;
    const int row0 = blockIdx.y * BM, col0 = blockIdx.x * BN;
    const int tid = threadIdx.x, l = tid & 63, w = tid >> 6;
    const int wm = w / WAVES_N, wn = w % WAVES_N;
    const int fr = l & 15, fq = l >> 4;

    f32x4 acc[MT][NT] = {};
    constexpr int ACALLS = (BM * BK) / (256 * 8);
    constexpr int BCALLS = (BN * BK) / (256 * 8);

    for (int kt = 0; kt < K; kt += BK) {
#pragma unroll
        for (int c = 0; c < ACALLS; ++c) {
            const int e = (c * 256 + tid) * 8;
            const long g = (long)(row0 + (e >> 5)) * K + kt + (e & 31);
            gload_lds16(Ah + g, &Ash[e]);
            gload_lds16(Al + g, &Asl[e]);
        }
#pragma unroll
        for (int c = 0; c < BCALLS; ++c) {
            const int e = (c * 256 + tid) * 8;
            const long g = (long)(col0 + (e >> 5)) * K + kt + (e & 31);
            gload_lds16(Bh + g, &Bsh[e]);
            gload_lds16(Bl + g, &Bsl[e]);
        }
        __syncthreads();

        bf16x8 afh[MT], afl[MT], bfh[NT], bfl[NT];
#pragma unroll
        for (int m = 0; m < MT; ++m) {
            const int o = (wm * WM + m * 16 + fr) * BK + fq * 8;
            afh[m] = __builtin_bit_cast(bf16x8, *(const u16x8*)&Ash[o]);
            afl[m] = __builtin_bit_cast(bf16x8, *(const u16x8*)&Asl[o]);
        }
#pragma unroll
        for (int n = 0; n < NT; ++n) {
            const int o = (wn * WN + n * 16 + fr) * BK + fq * 8;
            bfh[n] = __builtin_bit_cast(bf16x8, *(const u16x8*)&Bsh[o]);
            bfl[n] = __builtin_bit_cast(bf16x8, *(const u16x8*)&Bsl[o]);
        }
#pragma unroll
        for (int m = 0; m < MT; ++m)
#pragma unroll
            for (int n = 0; n < NT; ++n) {
                acc[m][n] = __builtin_amdgcn_mfma_f32_16x16x32_bf16(afh[m], bfh[n], acc[m][n], 0, 0, 0);
                acc[m][n] = __builtin_amdgcn_mfma_f32_16x16x32_bf16(afh[m], bfl[n], acc[m][n], 0, 0, 0);
                acc[m][n] = __builtin_amdgcn_mfma_f32_16x16x32_bf16(afl[m], bfh[n], acc[m][n], 0, 0, 0);
            }
        __syncthreads();
    }

#pragma unroll
    for (int m = 0; m < MT; ++m) {
        const int gr = row0 + wm * WM + m * 16 + fq * 4;
#pragma unroll
        for (int n = 0; n < NT; ++n) {
            const int gc = col0 + wn * WN + n * 16 + fr;
#pragma unroll
            for (int j = 0; j < 4; ++j) {
                const float v = acc[m][n][j] * alpha;
                const long idx = (long)bz * sC + (long)(gr + j) * N + gc;
                if (OUTMODE == 0) {
                    ((float*)out1)[idx] = v;
                } else {
                    const unsigned short h = f2bf(v);
                    ((unsigned short*)out1)[idx] = h;
                    out2[idx] = f2bf(v - bf2f(h));
                }
            }
        }
    }
}

// ---------------------------------------------------------------------------
// Plain bf16 GEMM: C[M,N] = alpha * A[M,K] @ B[N,K]^T  (batched via blockIdx.z)
template<int BM, int BN, int WAVES_M, int WAVES_N, bool OUT_F32>
__global__ __launch_bounds__(256)
void gemm_bt(const unsigned short* __restrict__ A,
             const unsigned short* __restrict__ B,
             void* __restrict__ Cv,
             int N, int K, long sA, long sB, long sC, float alpha)
{
    constexpr int BK = 32;
    constexpr int WM = BM / WAVES_M, WN = BN / WAVES_N;
    constexpr int MT = WM / 16, NT = WN / 16;
    __shared__ alignas(16) unsigned short As[BM * BK];
    __shared__ alignas(16) unsigned short Bs[BN * BK];

    const int bz = blockIdx.z;
    A += (long)bz * sA;
    B += (long)bz * sB;
    const int row0 = blockIdx.y * BM, col0 = blockIdx.x * BN;
    const int tid = threadIdx.x, l = tid & 63, w = tid >> 6;
    const int wm = w / WAVES_N, wn = w % WAVES_N;
    const int fr = l & 15, fq = l >> 4;

    f32x4 acc[MT][NT] = {};
    constexpr int ACALLS = (BM * BK) / (256 * 8);
    constexpr int BCALLS = (BN * BK) / (256 * 8);

    for (int kt = 0; kt < K; kt += BK) {
#pragma unroll
        for (int c = 0; c < ACALLS; ++c) {
            const int e = (c * 256 + tid) * 8;
            gload_lds16(A + (long)(row0 + (e >> 5)) * K + kt + (e & 31), &As[e]);
        }
#pragma unroll
        for (int c = 0; c < BCALLS; ++c) {
            const int e = (c * 256 + tid) * 8;
            gload_lds16(B + (long)(col0 + (e >> 5)) * K + kt + (e & 31), &Bs[e]);
        }
        __syncthreads();

        bf16x8 af[MT], bfr[NT];
#pragma unroll
        for (int m = 0; m < MT; ++m)
            af[m] = __builtin_bit_cast(bf16x8, *(const u16x8*)&As[(wm * WM + m * 16 + fr) * BK + fq * 8]);
#pragma unroll
        for (int n = 0; n < NT; ++n)
            bfr[n] = __builtin_bit_cast(bf16x8, *(const u16x8*)&Bs[(wn * WN + n * 16 + fr) * BK + fq * 8]);
#pragma unroll
        for (int m = 0; m < MT; ++m)
#pragma unroll
            for (int n = 0; n < NT; ++n)
                acc[m][n] = __builtin_amdgcn_mfma_f32_16x16x32_bf16(af[m], bfr[n], acc[m][n], 0, 0, 0);
        __syncthreads();
    }

#pragma unroll
    for (int m = 0; m < MT; ++m) {
        const int gr = row0 + wm * WM + m * 16 + fq * 4;
#pragma unroll
        for (int n = 0; n < NT; ++n) {
            const int gc = col0 + wn * WN + n * 16 + fr;
#pragma unroll
            for (int j = 0; j < 4; ++j) {
                const float v = acc[m][n][j] * alpha;
                if (OUT_F32) ((float*)Cv)[(long)bz * sC + (long)(gr + j) * N + gc] = v;
                else ((unsigned short*)Cv)[(long)bz * sC + (long)(gr + j) * N + gc] = f2bf(v);
            }
        }
    }
}

// ---------------------------------------------------------------------------
// P GEMM with fused row-sum normalization:
// C[M,N] = (1/(rowsum(A)+eps)) * A[M,K] @ B[K,N]  (bf16; B row-major [K x N]).
template<int BM, int BN, int WAVES_M, int WAVES_N>
__global__ __launch_bounds__(256)
void gemm_nt_rs(const unsigned short* __restrict__ A,
                const unsigned short* __restrict__ Bm,
                unsigned short* __restrict__ C,
                int N, int K, long sA, long sB, long sC)
{
    constexpr int BK = 32;
    constexpr int WM = BM / WAVES_M, WN = BN / WAVES_N;
    constexpr int MT = WM / 16, NT = WN / 16;
    __shared__ alignas(16) unsigned short As[BM * BK];
    __shared__ alignas(16) unsigned short Bs[BN * BK];   // Bs[col*BK + k]
    __shared__ float rsums[BM];

    const int bz = blockIdx.z;
    A += (long)bz * sA;
    Bm += (long)bz * sB;
    const int row0 = blockIdx.y * BM, col0 = blockIdx.x * BN;
    const int tid = threadIdx.x, l = tid & 63, w = tid >> 6;
    const int wm = w / WAVES_N, wn = w % WAVES_N;
    const int fr = l & 15, fq = l >> 4;

    f32x4 acc[MT][NT] = {};
    float rsum = 0.f;
    constexpr int ACALLS = (BM * BK) / (256 * 8);
    constexpr int TPR = BN / 8;
    constexpr int RPP = 256 / TPR;
    const int br = tid / TPR, bc8 = (tid % TPR) * 8;

    for (int kt = 0; kt < K; kt += BK) {
#pragma unroll
        for (int c = 0; c < ACALLS; ++c) {
            const int e = (c * 256 + tid) * 8;
            gload_lds16(A + (long)(row0 + (e >> 5)) * K + kt + (e & 31), &As[e]);
        }
#pragma unroll
        for (int p = 0; p < BK / RPP; ++p) {
            const int r = p * RPP + br;
            u16x8 vv = *(const u16x8*)(Bm + (long)(kt + r) * N + col0 + bc8);
#pragma unroll
            for (int j = 0; j < 8; ++j) Bs[(bc8 + j) * BK + r] = vv[j];
        }
        __syncthreads();

        if (tid < BM) {
#pragma unroll
            for (int kk = 0; kk < BK / 8; ++kk) {
                u16x8 vv = *(const u16x8*)&As[tid * BK + kk * 8];
#pragma unroll
                for (int j = 0; j < 8; ++j) rsum += bf2f(vv[j]);
            }
        }

        bf16x8 af[MT], bfr[NT];
#pragma unroll
        for (int m = 0; m < MT; ++m)
            af[m] = __builtin_bit_cast(bf16x8, *(const u16x8*)&As[(wm * WM + m * 16 + fr) * BK + fq * 8]);
#pragma unroll
        for (int n = 0; n < NT; ++n)
            bfr[n] = __builtin_bit_cast(bf16x8, *(const u16x8*)&Bs[(wn * WN + n * 16 + fr) * BK + fq * 8]);
#pragma unroll
        for (int m = 0; m < MT; ++m)
#pragma unroll
            for (int n = 0; n < NT; ++n)
                acc[m][n] = __builtin_amdgcn_mfma_f32_16x16x32_bf16(af[m], bfr[n], acc[m][n], 0, 0, 0);
        __syncthreads();
    }

    if (tid < BM) rsums[tid] = rsum;
    __syncthreads();

#pragma unroll
    for (int m = 0; m < MT; ++m) {
        const int lr = wm * WM + m * 16 + fq * 4;
        const int gr = row0 + lr;
#pragma unroll
        for (int n = 0; n < NT; ++n) {
            const int gc = col0 + wn * WN + n * 16 + fr;
#pragma unroll
            for (int j = 0; j < 4; ++j) {
                const float inv = 1.f / (rsums[lr + j] + 1e-8f);
                C[(long)bz * sC + (long)(gr + j) * N + gc] = f2bf(acc[m][n][j] * inv);
            }
        }
    }
}

// ---------------------------------------------------------------------------
// Fused LayerNorm (features + slots) over D=768, f32 in -> split hi/lo bf16.
// One wave per row; 3 passes, pass p: lane i handles elems [p*256 + 4i, +4).
// All loads 16B-contiguous per wave; stores 8B-contiguous.
__global__ __launch_bounds__(256)
void ln_fused(const float* __restrict__ xf, const float* __restrict__ gf,
              const float* __restrict__ bf,
              unsigned short* __restrict__ fh, unsigned short* __restrict__ fl,
              const float* __restrict__ xs, const float* __restrict__ gs,
              const float* __restrict__ bs,
              unsigned short* __restrict__ sh, unsigned short* __restrict__ sl,
              int nrows_f)
{
    constexpr int D = 768;
    const int lane = threadIdx.x & 63;
    long row = (long)blockIdx.x * 4 + (threadIdx.x >> 6);
    const float *x, *g, *bb_;
    unsigned short *yh, *yl;
    if (row < nrows_f) { x = xf; g = gf; bb_ = bf; yh = fh; yl = fl; }
    else { row -= nrows_f; x = xs; g = gs; bb_ = bs; yh = sh; yl = sl; }

    const float* xr = x + row * D;
    float v[12];
#pragma unroll
    for (int p = 0; p < 3; ++p) {
        fl4 t = *(const fl4*)(xr + p * 256 + lane * 4);
#pragma unroll
        for (int j = 0; j < 4; ++j) v[p * 4 + j] = t[j];
    }
    float s = 0.f, s2 = 0.f;
#pragma unroll
    for (int j = 0; j < 12; ++j) { s += v[j]; s2 += v[j] * v[j]; }
#pragma unroll
    for (int o = 1; o < 64; o <<= 1) { s += __shfl_xor(s, o); s2 += __shfl_xor(s2, o); }
    const float mu  = s / (float)D;
    const float var = s2 / (float)D - mu * mu;
    const float r   = rsqrtf(var + 1e-5f);

#pragma unroll
    for (int p = 0; p < 3; ++p) {
        fl4 gg = *(const fl4*)(g + p * 256 + lane * 4);
        fl4 be = *(const fl4*)(bb_ + p * 256 + lane * 4);
        u16x4 oh, ol;
#pragma unroll
        for (int j = 0; j < 4; ++j) {
            const float y = (v[p * 4 + j] - mu) * r * gg[j] + be[j];
            oh[j] = f2bf(y);
            ol[j] = f2bf(y - bf2f(oh[j]));
        }
        *(u16x4*)(yh + row * D + p * 256 + lane * 4) = oh;
        *(u16x4*)(yl + row * D + p * 256 + lane * 4) = ol;
    }
}

// ---------------------------------------------------------------------------
// normmax (alpha=5) over C=64 slots per (b,n) column.
// 34 bisections (== reference's 50 in f32), raw v_sqrt for u^(1/4).
__global__ __launch_bounds__(256)
void normmax_cols(const float* __restrict__ logits, const int* __restrict__ mask,
                  float* __restrict__ attn_f32, unsigned short* __restrict__ attn_b16)
{
    constexpr int N = 1024, C = 64;
    const int b = blockIdx.y;
    const int tid = threadIdx.x, l = tid & 63, w = tid >> 6;
    const int n = blockIdx.x * 64 + w * 16 + (l & 15);
    const int cb = (l >> 4) * 16;
    const long base = (long)b * C * N + n;
    const float* Lb = logits + base;
    const int m = mask[b * N + n];

    float z[16];
#pragma unroll
    for (int i = 0; i < 16; ++i) z[i] = m ? Lb[(cb + i) * N] : 0.f;

    float mx = z[0];
#pragma unroll
    for (int i = 1; i < 16; ++i) mx = fmaxf(mx, z[i]);
    mx = fmaxf(mx, __shfl_xor(mx, 16));
    mx = fmaxf(mx, __shfl_xor(mx, 32));

    float lo = mx - 1.f, hi = mx;
    for (int it = 0; it < 34; ++it) {
        const float tau = 0.5f * (lo + hi);
        float f = 0.f;
#pragma unroll
        for (int i = 0; i < 16; ++i) {
            const float u = fmaxf(z[i] - tau, 0.f);
            f += u * sqrt_raw(sqrt_raw(u));       // u^(5/4)
        }
        f += __shfl_xor(f, 16);
        f += __shfl_xor(f, 32);
        if (f >= 1.f) lo = tau; else hi = tau;
    }
    const float tau = 0.5f * (lo + hi);
    float sv[16]; float ss = 0.f;
#pragma unroll
    for (int i = 0; i < 16; ++i) {
        const float u = fmaxf(z[i] - tau, 0.f);
        sv[i] = sqrt_raw(sqrt_raw(u));            // u^(1/4)
        ss += sv[i];
    }
    ss += __shfl_xor(ss, 16);
    ss += __shfl_xor(ss, 32);
    const float inv = 1.f / ss;
#pragma unroll
    for (int i = 0; i < 16; ++i) {
        const float a = m ? sv[i] * inv : 0.f;
        attn_f32[base + (long)(cb + i) * N] = a;
        attn_b16[base + (long)(cb + i) * N] = f2bf(a);
    }
}

// ---------------------------------------------------------------------------
// torch GRUCell gates (r,z,n order), h_new = (1-z)*n + z*h. f32 in/out, x4 vec.
__global__ __launch_bounds__(256)
void gru_gates(const float* __restrict__ gi, const float* __restrict__ gh,
               const float* __restrict__ b_ih, const float* __restrict__ b_hh,
               const float* __restrict__ h, float* __restrict__ out)
{
    constexpr int D = 768;
    const int t = blockIdx.x * 256 + threadIdx.x;
    const int row = t / (D / 4), d = (t - row * (D / 4)) * 4;
    const float* gir = gi + (long)row * 3 * D;
    const float* ghr = gh + (long)row * 3 * D;
    fl4 ir  = *(const fl4*)(gir + d);
    fl4 iz  = *(const fl4*)(gir + D + d);
    fl4 in_ = *(const fl4*)(gir + 2 * D + d);
    fl4 hr  = *(const fl4*)(ghr + d);
    fl4 hz  = *(const fl4*)(ghr + D + d);
    fl4 hn  = *(const fl4*)(ghr + 2 * D + d);
    fl4 bir = *(const fl4*)(b_ih + d);
    fl4 biz = *(const fl4*)(b_ih + D + d);
    fl4 bin = *(const fl4*)(b_ih + 2 * D + d);
    fl4 bhr = *(const fl4*)(b_hh + d);
    fl4 bhz = *(const fl4*)(b_hh + D + d);
    fl4 bhn = *(const fl4*)(b_hh + 2 * D + d);
    fl4 hv  = *(const fl4*)(h + (long)row * D + d);
    fl4 o;
#pragma unroll
    for (int j = 0; j < 4; ++j) {
        const float r  = 1.f / (1.f + expf(-(ir[j] + bir[j] + hr[j] + bhr[j])));
        const float zg = 1.f / (1.f + expf(-(iz[j] + biz[j] + hz[j] + bhz[j])));
        const float ng = tanhf(in_[j] + bin[j] + r * (hn[j] + bhn[j]));
        o[j] = (1.f - zg) * ng + zg * hv[j];
    }
    *(fl4*)(out + (long)row * D + d) = o;
}

extern "C" void kernel_launch(void* const* d_in, const int* in_sizes, int n_in,
                              void* d_out, int out_size, void* d_ws, size_t ws_size,
                              hipStream_t stream)
{
    const float* features = (const float*)d_in[0];
    const float* slots    = (const float*)d_in[1];
    const int*   mask     = (const int*)d_in[2];
    const float* lnf_g = (const float*)d_in[3];
    const float* lnf_b = (const float*)d_in[4];
    const float* lns_g = (const float*)d_in[5];
    const float* lns_b = (const float*)d_in[6];
    const float* Wk  = (const float*)d_in[7];
    const float* Wv  = (const float*)d_in[8];
    const float* Wq  = (const float*)d_in[9];
    const float* Wih = (const float*)d_in[10];
    const float* Whh = (const float*)d_in[11];
    const float* bih = (const float*)d_in[12];
    const float* bhh = (const float*)d_in[13];

    constexpr int B = 32, N = 1024, C = 64, D = 768;
    char* ws = (char*)d_ws;
    // ---- workspace layout, peak ~128.7 MB
    unsigned short* f_hi = (unsigned short*)(ws + 0);          // [LN .. P gemm] 50,331,648
    float*          gi   = (float*)(ws + 0);                   // [gih gemm .. gru]
    float*          gh   = (float*)(ws + 18874368);            // contiguous after gi
    unsigned short* Wihb = (unsigned short*)(ws + 37748736);   // [conv2 .. gih gemm]
    unsigned short* Whhb = (unsigned short*)(ws + 41287680);   // contiguous after Wihb
    unsigned short* Wvb  = (unsigned short*)(ws + 44826624);   // [conv2 .. upd gemm]
    unsigned short* f_lo = (unsigned short*)(ws + 50331648);   // [LN .. logits] 50,331,648
    unsigned short* ab16 = (unsigned short*)(ws + 50331648);   // [normmax .. P gemm]
    unsigned short* Pbf  = (unsigned short*)(ws + 54525952);   // [P gemm .. upd gemm]
    unsigned short* updb = (unsigned short*)(ws + 57671680);   // [upd gemm .. gih gemm]
    unsigned short* slb  = (unsigned short*)(ws + 60817408);   // contiguous after updb
    float*          lg     = (float*)(ws + 100663296);          //  8,388,608
    unsigned short* s_hi   = (unsigned short*)(ws + 109051904); //  3,145,728
    unsigned short* s_lo   = (unsigned short*)(ws + 112197632);
    unsigned short* qk_hi  = (unsigned short*)(ws + 115343360);
    unsigned short* qk_lo  = (unsigned short*)(ws + 118489088);
    unsigned short* WqT_hi = (unsigned short*)(ws + 121634816); //  1,179,648
    unsigned short* WqT_lo = (unsigned short*)(ws + 122814464);
    unsigned short* WkT_hi = (unsigned short*)(ws + 123994112);
    unsigned short* WkT_lo = (unsigned short*)(ws + 125173760);
    unsigned short* MT_hi  = (unsigned short*)(ws + 126353408);
    unsigned short* MT_lo  = (unsigned short*)(ws + 127533056); // ends 128,712,704

    float* out_slots = (float*)d_out;
    float* out_attn  = out_slots + (long)B * C * D;

    // conv1: fused transpose+split of Wq, Wk
    tr2_f2b_split<<<(2 * D * D + 255) / 256, 256, 0, stream>>>(
        Wq, Wk, WqT_hi, WqT_lo, WkT_hi, WkT_lo);

    // fused LN (features + slots): (B*N + B*C)/4 blocks
    ln_fused<<<(B * N + B * C) / 4, 256, 0, stream>>>(
        features, lnf_g, lnf_b, f_hi, f_lo,
        slots, lns_g, lns_b, s_hi, s_lo, B * N);

    // M[j,i] = sum_k Wk[k,j]*Wq[k,i]  [768 x 768], split out
    gemm_bt3<64, 64, 2, 2, 1><<<dim3(D / 64, D / 64, 1), 256, 0, stream>>>(
        WkT_hi, WkT_lo, WqT_hi, WqT_lo, MT_hi, MT_lo, D, D, 0, 0, 0, 1.f);
    // qk = s @ M^T   [2048 x 768], split out
    gemm_bt3<64, 64, 2, 2, 1><<<dim3(D / 64, (B * C) / 64, 1), 256, 0, stream>>>(
        s_hi, s_lo, MT_hi, MT_lo, qk_hi, qk_lo, D, D, 0, 0, 0, 1.f);
    // logits[b] = qk_b @ f_b^T / sqrt(768)   [64 x 1024] f32
    gemm_bt3<64, 64, 2, 2, 0><<<dim3(N / 64, 1, B), 256, 0, stream>>>(
        qk_hi, qk_lo, f_hi, f_lo, lg, nullptr,
        N, D, (long)C * D, (long)N * D, (long)C * N, 0.03608439182435161f);

    // normmax -> f32 attn (d_out) + bf16 copy
    normmax_cols<<<dim3(N / 64, B), 256, 0, stream>>>(lg, mask, out_attn, ab16);

    // P[b] = diag(1/(rowsum+eps)) * attn_b @ f_b   [64 x 768], K=1024
    gemm_nt_rs<64, 64, 2, 2><<<dim3(D / 64, 1, B), 256, 0, stream>>>(
        ab16, f_hi, Pbf, D, N, (long)C * N, (long)N * D, (long)C * D);

    // conv2: fused GRU-path conversions (into dead f_hi / f_lo zones)
    {
        constexpr int TOT = 3 * D * D + 3 * D * D + B * C * D + D * D;
        conv2_fused<<<(TOT / 4 + 255) / 256, 256, 0, stream>>>(
            Wih, Whh, slots, Wv, Wihb, Whhb, slb, Wvb);
    }

    // upd = P @ Wv^T   [2048 x 768]
    gemm_bt<64, 64, 2, 2, false><<<dim3(D / 64, (B * C) / 64, 1), 256, 0, stream>>>(
        Pbf, Wvb, updb, D, D, 0, 0, 0, 1.f);

    // gi = upd @ W_ih^T ; gh = slots @ W_hh^T  — batched via blockIdx.z
    gemm_bt<128, 128, 2, 2, true><<<dim3(3 * D / 128, (B * C) / 128, 2), 256, 0, stream>>>(
        updb, Wihb, gi, 3 * D, D,
        (long)(B * C) * D, (long)(3 * D) * D, (long)(B * C) * 3 * D, 1.f);

    gru_gates<<<(B * C * D / 4) / 256, 256, 0, stream>>>(gi, gh, bih, bhh, slots, out_slots);
}